// Round 1
// baseline (23716.592 us; speedup 1.0000x reference)
//
#include <hip/hip_runtime.h>

#define D 128

// ---------------- CSR build ----------------

__global__ void zero_int_kernel(int* __restrict__ p, int n) {
    int i = blockIdx.x * blockDim.x + threadIdx.x;
    if (i < n) p[i] = 0;
}

__global__ void count_deg_kernel(const int* __restrict__ dst, int* __restrict__ deg, int E) {
    int i = blockIdx.x * blockDim.x + threadIdx.x;
    if (i < E) atomicAdd(&deg[dst[i]], 1);
}

// single-block exclusive scan over n (<= 1024*chunk) ints
__global__ __launch_bounds__(1024) void scan_kernel(const int* __restrict__ deg,
                                                    int* __restrict__ rowptr, int n) {
    __shared__ int sums[1024];
    int t = threadIdx.x;
    int chunk = (n + 1023) >> 10;
    int s0 = t * chunk;
    int s1 = min(s0 + chunk, n);
    int s = 0;
    for (int i = s0; i < s1; ++i) s += deg[i];
    sums[t] = s;
    __syncthreads();
    for (int off = 1; off < 1024; off <<= 1) {
        int v = (t >= off) ? sums[t - off] : 0;
        __syncthreads();
        sums[t] += v;
        __syncthreads();
    }
    int excl = (t > 0) ? sums[t - 1] : 0;
    for (int i = s0; i < s1; ++i) { rowptr[i] = excl; excl += deg[i]; }
    if (t == 1023) rowptr[n] = sums[1023];
}

__global__ void fill_csr_kernel(const int* __restrict__ src, const int* __restrict__ dst,
                                const int* __restrict__ rowptr, int* __restrict__ cursor,
                                int* __restrict__ col, int E) {
    int i = blockIdx.x * blockDim.x + threadIdx.x;
    if (i < E) {
        int d = dst[i];
        int pos = atomicAdd(&cursor[d], 1);
        col[rowptr[d] + pos] = src[i];
    }
}

// ---------------- segment mean (one wave per destination row) ----------------

__global__ __launch_bounds__(256) void agg_mean_kernel(
    const float* __restrict__ hsrc, const int* __restrict__ rowptr,
    const int* __restrict__ col, float* __restrict__ out, int ndst) {
    int w = (blockIdx.x * blockDim.x + threadIdx.x) >> 6;   // wave id = dst row
    int lane = threadIdx.x & 63;
    if (w >= ndst) return;
    int beg = rowptr[w];
    int end = rowptr[w + 1];
    float ax = 0.f, ay = 0.f;
    for (int e = beg; e < end; ++e) {
        int s = col[e];
        float2 v = *(const float2*)(hsrc + (size_t)s * D + lane * 2);
        ax += v.x; ay += v.y;
    }
    float inv = 1.0f / fmaxf((float)(end - beg), 1.0f);
    float2 r; r.x = ax * inv; r.y = ay * inv;
    *(float2*)(out + (size_t)w * D + lane * 2) = r;
}

// ---------------- fused SAGE layer: Y = relu(A@W1 + B@W2 + bias) [+= if ACC] ----------------
// BM=64 rows, BN=128 (full width), BK=16. 256 threads; 8 rows x 4 cols per thread.

template<bool ACC>
__global__ __launch_bounds__(256) void sage_gemm_kernel(
    const float* __restrict__ A, const float* __restrict__ B,
    const float* __restrict__ W1, const float* __restrict__ W2,
    const float* __restrict__ bias, float* __restrict__ Y, int M)
{
    __shared__ float As[16][64];
    __shared__ float Ws[16][128];
    int tid = threadIdx.x;
    int tx = tid & 31;        // col group: cols tx*4 .. tx*4+3
    int ty = tid >> 5;        // row group: rows ty*8 .. ty*8+7
    int row0 = blockIdx.x * 64;

    int la_row = tid >> 2;          // 0..63
    int la_k   = (tid & 3) * 4;     // 0,4,8,12
    int lw_n   = (tid & 31) * 4;    // 0..124
    int lw_k   = tid >> 5;          // 0..7

    float acc[8][4];
    #pragma unroll
    for (int r = 0; r < 8; ++r)
        #pragma unroll
        for (int c = 0; c < 4; ++c) acc[r][c] = 0.f;

    #pragma unroll
    for (int half = 0; half < 2; ++half) {
        const float* Ain = half ? B : A;
        const float* Win = half ? W2 : W1;
        #pragma unroll
        for (int k0 = 0; k0 < 128; k0 += 16) {
            int grow = row0 + la_row;
            float4 av = make_float4(0.f, 0.f, 0.f, 0.f);
            if (grow < M) av = *(const float4*)(Ain + (size_t)grow * D + k0 + la_k);
            float4 wv0 = *(const float4*)(Win + (size_t)(k0 + lw_k) * D + lw_n);
            float4 wv1 = *(const float4*)(Win + (size_t)(k0 + lw_k + 8) * D + lw_n);
            __syncthreads();
            As[la_k + 0][la_row] = av.x;
            As[la_k + 1][la_row] = av.y;
            As[la_k + 2][la_row] = av.z;
            As[la_k + 3][la_row] = av.w;
            *(float4*)&Ws[lw_k][lw_n]     = wv0;
            *(float4*)&Ws[lw_k + 8][lw_n] = wv1;
            __syncthreads();
            #pragma unroll
            for (int k = 0; k < 16; ++k) {
                float4 w  = *(const float4*)&Ws[k][tx * 4];
                float4 a0 = *(const float4*)&As[k][ty * 8];
                float4 a1 = *(const float4*)&As[k][ty * 8 + 4];
                float a[8] = {a0.x, a0.y, a0.z, a0.w, a1.x, a1.y, a1.z, a1.w};
                float wr[4] = {w.x, w.y, w.z, w.w};
                #pragma unroll
                for (int r = 0; r < 8; ++r)
                    #pragma unroll
                    for (int c = 0; c < 4; ++c)
                        acc[r][c] = fmaf(a[r], wr[c], acc[r][c]);
            }
        }
    }

    float4 bv = *(const float4*)(bias + tx * 4);
    #pragma unroll
    for (int r = 0; r < 8; ++r) {
        int grow = row0 + ty * 8 + r;
        if (grow < M) {
            float4 t;
            t.x = fmaxf(acc[r][0] + bv.x, 0.f);
            t.y = fmaxf(acc[r][1] + bv.y, 0.f);
            t.z = fmaxf(acc[r][2] + bv.z, 0.f);
            t.w = fmaxf(acc[r][3] + bv.w, 0.f);
            float4* yp = (float4*)(Y + (size_t)grow * D + tx * 4);
            if (ACC) {
                float4 o = *yp;
                t.x += o.x; t.y += o.y; t.z += o.z; t.w += o.w;
            }
            *yp = t;
        }
    }
}

// ---------------- launch ----------------

extern "C" void kernel_launch(void* const* d_in, const int* in_sizes, int n_in,
                              void* d_out, int out_size, void* d_ws, size_t ws_size,
                              hipStream_t stream) {
    const float* h_station = (const float*)d_in[0];
    const float* h_feature = (const float*)d_in[1];
    const float* Wself     = (const float*)d_in[2];
    const float* Wneigh    = (const float*)d_in[3];
    const float* bias      = (const float*)d_in[4];
    const int* hf_src = (const int*)d_in[5];
    const int* hf_dst = (const int*)d_in[6];
    const int* tt_src = (const int*)d_in[7];
    const int* tt_dst = (const int*)d_in[8];

    const int NS = in_sizes[0] / D;
    const int E1 = in_sizes[5];
    const int E2 = in_sizes[7];

    // workspace carve-up
    char* ws = (char*)d_ws;
    size_t off = 0;
    auto alloc = [&](size_t bytes) -> void* {
        void* p = ws + off;
        off = (off + bytes + 255) & ~(size_t)255;
        return p;
    };
    float* n_buf  = (float*)alloc((size_t)NS * D * sizeof(float));
    float* h_buf  = (float*)alloc((size_t)NS * D * sizeof(float));
    int* rp_hf    = (int*)alloc((size_t)(NS + 1) * sizeof(int));
    int* col_hf   = (int*)alloc((size_t)E1 * sizeof(int));
    int* rp_tt    = (int*)alloc((size_t)(NS + 1) * sizeof(int));
    int* col_tt   = (int*)alloc((size_t)E2 * sizeof(int));
    int* deg      = (int*)alloc((size_t)NS * sizeof(int));
    int* cursor   = (int*)alloc((size_t)NS * sizeof(int));

    const int tpb = 256;
    int gz  = (NS + tpb - 1) / tpb;
    int ge1 = (E1 + tpb - 1) / tpb;
    int ge2 = (E2 + tpb - 1) / tpb;

    // build hf CSR (feature -> station)
    zero_int_kernel<<<gz, tpb, 0, stream>>>(deg, NS);
    count_deg_kernel<<<ge1, tpb, 0, stream>>>(hf_dst, deg, E1);
    scan_kernel<<<1, 1024, 0, stream>>>(deg, rp_hf, NS);
    zero_int_kernel<<<gz, tpb, 0, stream>>>(cursor, NS);
    fill_csr_kernel<<<ge1, tpb, 0, stream>>>(hf_src, hf_dst, rp_hf, cursor, col_hf, E1);

    // build tt CSR (station -> station)
    zero_int_kernel<<<gz, tpb, 0, stream>>>(deg, NS);
    count_deg_kernel<<<ge2, tpb, 0, stream>>>(tt_dst, deg, E2);
    scan_kernel<<<1, 1024, 0, stream>>>(deg, rp_tt, NS);
    zero_int_kernel<<<gz, tpb, 0, stream>>>(cursor, NS);
    fill_csr_kernel<<<ge2, tpb, 0, stream>>>(tt_src, tt_dst, rp_tt, cursor, col_tt, E2);

    int gagg  = (NS * 64 + tpb - 1) / tpb;   // one wave per dst row
    int ggemm = (NS + 63) / 64;

    auto WS = [&](int l, int r) { return Wself  + (size_t)(l * 2 + r) * D * D; };
    auto WN = [&](int l, int r) { return Wneigh + (size_t)(l * 2 + r) * D * D; };
    auto BI = [&](int l, int r) { return bias   + (size_t)(l * 2 + r) * D; };

    float* out = (float*)d_out;

    // ---- layer 1 ----
    agg_mean_kernel<<<gagg, tpb, 0, stream>>>(h_feature, rp_hf, col_hf, n_buf, NS);
    sage_gemm_kernel<false><<<ggemm, tpb, 0, stream>>>(h_station, n_buf, WS(0,0), WN(0,0), BI(0,0), h_buf, NS);
    agg_mean_kernel<<<gagg, tpb, 0, stream>>>(h_station, rp_tt, col_tt, n_buf, NS);
    sage_gemm_kernel<true><<<ggemm, tpb, 0, stream>>>(h_station, n_buf, WS(0,1), WN(0,1), BI(0,1), h_buf, NS);

    // ---- layer 2 (in-place on h_buf: each block only reads/writes its own rows) ----
    agg_mean_kernel<<<gagg, tpb, 0, stream>>>(h_buf, rp_tt, col_tt, n_buf, NS);
    sage_gemm_kernel<false><<<ggemm, tpb, 0, stream>>>(h_buf, n_buf, WS(1,1), WN(1,1), BI(1,1), h_buf, NS);

    // ---- layer 3 ----
    agg_mean_kernel<<<gagg, tpb, 0, stream>>>(h_buf, rp_tt, col_tt, n_buf, NS);
    sage_gemm_kernel<false><<<ggemm, tpb, 0, stream>>>(h_buf, n_buf, WS(2,1), WN(2,1), BI(2,1), out, NS);
}

// Round 2
// 771.672 us; speedup vs baseline: 30.7340x; 30.7340x over previous
//
#include <hip/hip_runtime.h>

#define D 128

// ---------------- CSR build ----------------

__global__ void zero_int_kernel(int* __restrict__ p, int n) {
    int i = blockIdx.x * blockDim.x + threadIdx.x;
    if (i < n) p[i] = 0;
}

__global__ void count_deg_kernel(const int* __restrict__ dst, int* __restrict__ deg, int E) {
    int i = blockIdx.x * blockDim.x + threadIdx.x;
    if (i < E) atomicAdd(&deg[dst[i]], 1);
}

// single-block exclusive scan over n ints
__global__ __launch_bounds__(1024) void scan_kernel(const int* __restrict__ deg,
                                                    int* __restrict__ rowptr, int n) {
    __shared__ int sums[1024];
    int t = threadIdx.x;
    int chunk = (n + 1023) >> 10;
    int s0 = t * chunk;
    int s1 = min(s0 + chunk, n);
    int s = 0;
    for (int i = s0; i < s1; ++i) s += deg[i];
    sums[t] = s;
    __syncthreads();
    for (int off = 1; off < 1024; off <<= 1) {
        int v = (t >= off) ? sums[t - off] : 0;
        __syncthreads();
        sums[t] += v;
        __syncthreads();
    }
    int excl = (t > 0) ? sums[t - 1] : 0;
    for (int i = s0; i < s1; ++i) { rowptr[i] = excl; excl += deg[i]; }
    if (t == 1023) rowptr[n] = sums[1023];
}

__global__ void fill_csr_kernel(const int* __restrict__ src, const int* __restrict__ dst,
                                const int* __restrict__ rowptr, int* __restrict__ cursor,
                                int* __restrict__ col, int E) {
    int i = blockIdx.x * blockDim.x + threadIdx.x;
    if (i < E) {
        int d = dst[i];
        int pos = atomicAdd(&cursor[d], 1);
        col[rowptr[d] + pos] = src[i];
    }
}

// ---------------- segment mean (one wave per destination row) ----------------

__global__ __launch_bounds__(256) void agg_mean_kernel(
    const float* __restrict__ hsrc, const int* __restrict__ rowptr,
    const int* __restrict__ col, float* __restrict__ out, int ndst) {
    int w = (blockIdx.x * blockDim.x + threadIdx.x) >> 6;   // wave id = dst row
    int lane = threadIdx.x & 63;
    if (w >= ndst) return;
    int beg = rowptr[w];
    int end = rowptr[w + 1];
    float ax = 0.f, ay = 0.f;
    for (int e = beg; e < end; ++e) {
        int s = col[e];
        float2 v = *(const float2*)(hsrc + (size_t)s * D + lane * 2);
        ax += v.x; ay += v.y;
    }
    float inv = 1.0f / fmaxf((float)(end - beg), 1.0f);
    float2 r; r.x = ax * inv; r.y = ay * inv;
    *(float2*)(out + (size_t)w * D + lane * 2) = r;
}

// ---------------- fused SAGE layer: Y = relu(A@W1 + B@W2 + bias) [+= if ACC] ----------------
// BM=64 rows, BN=128 (full width), BK=16. 256 threads; 8 rows x 4 cols per thread.
// NOTE: tile loops are pinned to unroll 1 — full unrolling spilled acc to scratch
// (round 1: VGPR=256, 9.6GB HBM traffic/dispatch, 5.8ms). Only the k=16 inner
// loop is unrolled (3x ds_read_b128 + 32 FMA per step).

template<bool ACC>
__global__ __launch_bounds__(256) void sage_gemm_kernel(
    const float* __restrict__ A, const float* __restrict__ B,
    const float* __restrict__ W1, const float* __restrict__ W2,
    const float* __restrict__ bias, float* __restrict__ Y, int M)
{
    __shared__ float As[16][64];
    __shared__ float Ws[16][128];
    int tid = threadIdx.x;
    int tx = tid & 31;        // col group: cols tx*4 .. tx*4+3
    int ty = tid >> 5;        // row group: rows ty*8 .. ty*8+7
    int row0 = blockIdx.x * 64;

    int la_row = tid >> 2;          // 0..63
    int la_k   = (tid & 3) * 4;     // 0,4,8,12
    int lw_n   = (tid & 31) * 4;    // 0..124
    int lw_k   = tid >> 5;          // 0..7

    float acc[8][4];
    #pragma unroll
    for (int r = 0; r < 8; ++r)
        #pragma unroll
        for (int c = 0; c < 4; ++c) acc[r][c] = 0.f;

    #pragma unroll 1
    for (int half = 0; half < 2; ++half) {
        const float* Ain = half ? B : A;
        const float* Win = half ? W2 : W1;
        #pragma unroll 1
        for (int k0 = 0; k0 < 128; k0 += 16) {
            int grow = row0 + la_row;
            float4 av = make_float4(0.f, 0.f, 0.f, 0.f);
            if (grow < M) av = *(const float4*)(Ain + (size_t)grow * D + k0 + la_k);
            float4 wv0 = *(const float4*)(Win + (size_t)(k0 + lw_k) * D + lw_n);
            float4 wv1 = *(const float4*)(Win + (size_t)(k0 + lw_k + 8) * D + lw_n);
            __syncthreads();
            As[la_k + 0][la_row] = av.x;
            As[la_k + 1][la_row] = av.y;
            As[la_k + 2][la_row] = av.z;
            As[la_k + 3][la_row] = av.w;
            *(float4*)&Ws[lw_k][lw_n]     = wv0;
            *(float4*)&Ws[lw_k + 8][lw_n] = wv1;
            __syncthreads();
            #pragma unroll
            for (int k = 0; k < 16; ++k) {
                float4 w  = *(const float4*)&Ws[k][tx * 4];
                float4 a0 = *(const float4*)&As[k][ty * 8];
                float4 a1 = *(const float4*)&As[k][ty * 8 + 4];
                float a[8] = {a0.x, a0.y, a0.z, a0.w, a1.x, a1.y, a1.z, a1.w};
                float wr[4] = {w.x, w.y, w.z, w.w};
                #pragma unroll
                for (int r = 0; r < 8; ++r)
                    #pragma unroll
                    for (int c = 0; c < 4; ++c)
                        acc[r][c] = fmaf(a[r], wr[c], acc[r][c]);
            }
        }
    }

    float4 bv = *(const float4*)(bias + tx * 4);
    #pragma unroll
    for (int r = 0; r < 8; ++r) {
        int grow = row0 + ty * 8 + r;
        if (grow < M) {
            float4 t;
            t.x = fmaxf(acc[r][0] + bv.x, 0.f);
            t.y = fmaxf(acc[r][1] + bv.y, 0.f);
            t.z = fmaxf(acc[r][2] + bv.z, 0.f);
            t.w = fmaxf(acc[r][3] + bv.w, 0.f);
            float4* yp = (float4*)(Y + (size_t)grow * D + tx * 4);
            if (ACC) {
                float4 o = *yp;
                t.x += o.x; t.y += o.y; t.z += o.z; t.w += o.w;
            }
            *yp = t;
        }
    }
}

// ---------------- launch ----------------

extern "C" void kernel_launch(void* const* d_in, const int* in_sizes, int n_in,
                              void* d_out, int out_size, void* d_ws, size_t ws_size,
                              hipStream_t stream) {
    const float* h_station = (const float*)d_in[0];
    const float* h_feature = (const float*)d_in[1];
    const float* Wself     = (const float*)d_in[2];
    const float* Wneigh    = (const float*)d_in[3];
    const float* bias      = (const float*)d_in[4];
    const int* hf_src = (const int*)d_in[5];
    const int* hf_dst = (const int*)d_in[6];
    const int* tt_src = (const int*)d_in[7];
    const int* tt_dst = (const int*)d_in[8];

    const int NS = in_sizes[0] / D;
    const int E1 = in_sizes[5];
    const int E2 = in_sizes[7];

    // workspace carve-up
    char* ws = (char*)d_ws;
    size_t off = 0;
    auto alloc = [&](size_t bytes) -> void* {
        void* p = ws + off;
        off = (off + bytes + 255) & ~(size_t)255;
        return p;
    };
    float* n_buf  = (float*)alloc((size_t)NS * D * sizeof(float));
    float* h_buf  = (float*)alloc((size_t)NS * D * sizeof(float));
    int* rp_hf    = (int*)alloc((size_t)(NS + 1) * sizeof(int));
    int* col_hf   = (int*)alloc((size_t)E1 * sizeof(int));
    int* rp_tt    = (int*)alloc((size_t)(NS + 1) * sizeof(int));
    int* col_tt   = (int*)alloc((size_t)E2 * sizeof(int));
    int* deg      = (int*)alloc((size_t)NS * sizeof(int));
    int* cursor   = (int*)alloc((size_t)NS * sizeof(int));

    const int tpb = 256;
    int gz  = (NS + tpb - 1) / tpb;
    int ge1 = (E1 + tpb - 1) / tpb;
    int ge2 = (E2 + tpb - 1) / tpb;

    // build hf CSR (feature -> station)
    zero_int_kernel<<<gz, tpb, 0, stream>>>(deg, NS);
    count_deg_kernel<<<ge1, tpb, 0, stream>>>(hf_dst, deg, E1);
    scan_kernel<<<1, 1024, 0, stream>>>(deg, rp_hf, NS);
    zero_int_kernel<<<gz, tpb, 0, stream>>>(cursor, NS);
    fill_csr_kernel<<<ge1, tpb, 0, stream>>>(hf_src, hf_dst, rp_hf, cursor, col_hf, E1);

    // build tt CSR (station -> station)
    zero_int_kernel<<<gz, tpb, 0, stream>>>(deg, NS);
    count_deg_kernel<<<ge2, tpb, 0, stream>>>(tt_dst, deg, E2);
    scan_kernel<<<1, 1024, 0, stream>>>(deg, rp_tt, NS);
    zero_int_kernel<<<gz, tpb, 0, stream>>>(cursor, NS);
    fill_csr_kernel<<<ge2, tpb, 0, stream>>>(tt_src, tt_dst, rp_tt, cursor, col_tt, E2);

    int gagg  = (NS * 64 + tpb - 1) / tpb;   // one wave per dst row
    int ggemm = (NS + 63) / 64;

    auto WS = [&](int l, int r) { return Wself  + (size_t)(l * 2 + r) * D * D; };
    auto WN = [&](int l, int r) { return Wneigh + (size_t)(l * 2 + r) * D * D; };
    auto BI = [&](int l, int r) { return bias   + (size_t)(l * 2 + r) * D; };

    float* out = (float*)d_out;

    // ---- layer 1 ----
    agg_mean_kernel<<<gagg, tpb, 0, stream>>>(h_feature, rp_hf, col_hf, n_buf, NS);
    sage_gemm_kernel<false><<<ggemm, tpb, 0, stream>>>(h_station, n_buf, WS(0,0), WN(0,0), BI(0,0), h_buf, NS);
    agg_mean_kernel<<<gagg, tpb, 0, stream>>>(h_station, rp_tt, col_tt, n_buf, NS);
    sage_gemm_kernel<true><<<ggemm, tpb, 0, stream>>>(h_station, n_buf, WS(0,1), WN(0,1), BI(0,1), h_buf, NS);

    // ---- layer 2 (in-place on h_buf: each block only reads/writes its own rows) ----
    agg_mean_kernel<<<gagg, tpb, 0, stream>>>(h_buf, rp_tt, col_tt, n_buf, NS);
    sage_gemm_kernel<false><<<ggemm, tpb, 0, stream>>>(h_buf, n_buf, WS(1,1), WN(1,1), BI(1,1), h_buf, NS);

    // ---- layer 3 ----
    agg_mean_kernel<<<gagg, tpb, 0, stream>>>(h_buf, rp_tt, col_tt, n_buf, NS);
    sage_gemm_kernel<false><<<ggemm, tpb, 0, stream>>>(h_buf, n_buf, WS(2,1), WN(2,1), BI(2,1), out, NS);
}

// Round 3
// 657.422 us; speedup vs baseline: 36.0751x; 1.1738x over previous
//
#include <hip/hip_runtime.h>

#define D 128

// ---------------- CSR build (both graphs fused) ----------------

__global__ void zero4_kernel(int* __restrict__ a, int* __restrict__ b,
                             int* __restrict__ c, int* __restrict__ d, int n) {
    int i = blockIdx.x * blockDim.x + threadIdx.x;
    if (i < n) { a[i] = 0; b[i] = 0; c[i] = 0; d[i] = 0; }
}

__global__ void count_both_kernel(const int* __restrict__ hf_dst, const int* __restrict__ tt_dst,
                                  int* __restrict__ deg_hf, int* __restrict__ deg_tt,
                                  int E1, int E2) {
    int i = blockIdx.x * blockDim.x + threadIdx.x;
    if (i < E1) atomicAdd(&deg_hf[hf_dst[i]], 1);
    if (i < E2) atomicAdd(&deg_tt[tt_dst[i]], 1);
}

__device__ void scan_one(const int* __restrict__ deg, int* __restrict__ rowptr, int n,
                         int* sums) {
    int t = threadIdx.x;
    int chunk = (n + 1023) >> 10;
    int s0 = t * chunk;
    int s1 = min(s0 + chunk, n);
    int s = 0;
    for (int i = s0; i < s1; ++i) s += deg[i];
    sums[t] = s;
    __syncthreads();
    for (int off = 1; off < 1024; off <<= 1) {
        int v = (t >= off) ? sums[t - off] : 0;
        __syncthreads();
        sums[t] += v;
        __syncthreads();
    }
    int excl = (t > 0) ? sums[t - 1] : 0;
    for (int i = s0; i < s1; ++i) { rowptr[i] = excl; excl += deg[i]; }
    if (t == 1023) rowptr[n] = sums[1023];
    __syncthreads();
}

__global__ __launch_bounds__(1024) void scan2_kernel(
    const int* __restrict__ deg_hf, int* __restrict__ rp_hf,
    const int* __restrict__ deg_tt, int* __restrict__ rp_tt, int n) {
    __shared__ int sums[1024];
    scan_one(deg_hf, rp_hf, n, sums);
    scan_one(deg_tt, rp_tt, n, sums);
}

__global__ void fill_both_kernel(
    const int* __restrict__ hf_src, const int* __restrict__ hf_dst,
    const int* __restrict__ rp_hf, int* __restrict__ cur_hf, int* __restrict__ col_hf,
    const int* __restrict__ tt_src, const int* __restrict__ tt_dst,
    const int* __restrict__ rp_tt, int* __restrict__ cur_tt, int* __restrict__ col_tt,
    int E1, int E2) {
    int i = blockIdx.x * blockDim.x + threadIdx.x;
    if (i < E1) {
        int d = hf_dst[i];
        int pos = atomicAdd(&cur_hf[d], 1);
        col_hf[rp_hf[d] + pos] = hf_src[i];
    }
    if (i < E2) {
        int d = tt_dst[i];
        int pos = atomicAdd(&cur_tt[d], 1);
        col_tt[rp_tt[d] + pos] = tt_src[i];
    }
}

// ---------------- segment mean (one wave per destination row) ----------------
// Round-2 profile: 81us each, VALUBusy 11%, hbm 26% -> latency-bound on the
// serial col[e] -> gather chain. Fix: coalesced index preload + shfl broadcast,
// 4-wide unrolled gathers into 4 independent accumulator sets.

__global__ __launch_bounds__(256) void agg_mean_kernel(
    const float* __restrict__ hsrc, const int* __restrict__ rowptr,
    const int* __restrict__ col, float* __restrict__ out, int ndst) {
    int w = (blockIdx.x * blockDim.x + threadIdx.x) >> 6;   // wave id = dst row
    int lane = threadIdx.x & 63;
    if (w >= ndst) return;
    int beg = rowptr[w];
    int end = rowptr[w + 1];
    int deg = end - beg;
    float ax0 = 0.f, ay0 = 0.f, ax1 = 0.f, ay1 = 0.f;
    float ax2 = 0.f, ay2 = 0.f, ax3 = 0.f, ay3 = 0.f;
    const float* base = hsrc + lane * 2;
    for (int b = beg; b < end; b += 64) {
        int n = min(64, end - b);
        int myidx = (lane < n) ? col[b + lane] : 0;
        int j = 0;
        for (; j + 4 <= n; j += 4) {
            int s0 = __shfl(myidx, j);
            int s1 = __shfl(myidx, j + 1);
            int s2 = __shfl(myidx, j + 2);
            int s3 = __shfl(myidx, j + 3);
            float2 v0 = *(const float2*)(base + (size_t)s0 * D);
            float2 v1 = *(const float2*)(base + (size_t)s1 * D);
            float2 v2 = *(const float2*)(base + (size_t)s2 * D);
            float2 v3 = *(const float2*)(base + (size_t)s3 * D);
            ax0 += v0.x; ay0 += v0.y;
            ax1 += v1.x; ay1 += v1.y;
            ax2 += v2.x; ay2 += v2.y;
            ax3 += v3.x; ay3 += v3.y;
        }
        for (; j < n; ++j) {
            int s0 = __shfl(myidx, j);
            float2 v0 = *(const float2*)(base + (size_t)s0 * D);
            ax0 += v0.x; ay0 += v0.y;
        }
    }
    float inv = 1.0f / fmaxf((float)deg, 1.0f);
    float2 r;
    r.x = ((ax0 + ax1) + (ax2 + ax3)) * inv;
    r.y = ((ay0 + ay1) + (ay2 + ay3)) * inv;
    *(float2*)(out + (size_t)w * D + lane * 2) = r;
}

// ---------------- fused SAGE layer: Y = relu(A@W1 + B@W2 + bias) [+= if ACC] ----------------
// BM=128, BN=128, BK=16. 256 threads; 8x8 micro-tile (64 FMA per 4 ds_read_b128).
// Tile loops pinned to unroll 1 — full unrolling spilled acc to scratch in round 1.

template<bool ACC>
__global__ __launch_bounds__(256) void sage_gemm_kernel(
    const float* __restrict__ A, const float* __restrict__ B,
    const float* __restrict__ W1, const float* __restrict__ W2,
    const float* __restrict__ bias, float* __restrict__ Y, int M)
{
    __shared__ float As[16][128];
    __shared__ float Ws[16][128];
    int tid = threadIdx.x;
    int tx = tid & 15;        // col group: cols tx*8 .. tx*8+7
    int ty = tid >> 4;        // row group: rows ty*8 .. ty*8+7
    int row0 = blockIdx.x * 128;

    int la_row = tid >> 1;          // 0..127
    int la_k   = (tid & 1) * 8;     // 0 or 8
    int lw_n   = (tid & 31) * 4;    // 0..124
    int lw_k   = tid >> 5;          // 0..7

    float acc[8][8];
    #pragma unroll
    for (int r = 0; r < 8; ++r)
        #pragma unroll
        for (int c = 0; c < 8; ++c) acc[r][c] = 0.f;

    #pragma unroll 1
    for (int half = 0; half < 2; ++half) {
        const float* Ain = half ? B : A;
        const float* Win = half ? W2 : W1;
        #pragma unroll 1
        for (int k0 = 0; k0 < 128; k0 += 16) {
            int grow = row0 + la_row;
            float4 av0 = make_float4(0.f, 0.f, 0.f, 0.f);
            float4 av1 = make_float4(0.f, 0.f, 0.f, 0.f);
            if (grow < M) {
                av0 = *(const float4*)(Ain + (size_t)grow * D + k0 + la_k);
                av1 = *(const float4*)(Ain + (size_t)grow * D + k0 + la_k + 4);
            }
            float4 wv0 = *(const float4*)(Win + (size_t)(k0 + lw_k) * D + lw_n);
            float4 wv1 = *(const float4*)(Win + (size_t)(k0 + lw_k + 8) * D + lw_n);
            __syncthreads();
            As[la_k + 0][la_row] = av0.x;
            As[la_k + 1][la_row] = av0.y;
            As[la_k + 2][la_row] = av0.z;
            As[la_k + 3][la_row] = av0.w;
            As[la_k + 4][la_row] = av1.x;
            As[la_k + 5][la_row] = av1.y;
            As[la_k + 6][la_row] = av1.z;
            As[la_k + 7][la_row] = av1.w;
            *(float4*)&Ws[lw_k][lw_n]     = wv0;
            *(float4*)&Ws[lw_k + 8][lw_n] = wv1;
            __syncthreads();
            #pragma unroll
            for (int k = 0; k < 16; ++k) {
                float4 w0 = *(const float4*)&Ws[k][tx * 8];
                float4 w1 = *(const float4*)&Ws[k][tx * 8 + 4];
                float4 a0 = *(const float4*)&As[k][ty * 8];
                float4 a1 = *(const float4*)&As[k][ty * 8 + 4];
                float a[8] = {a0.x, a0.y, a0.z, a0.w, a1.x, a1.y, a1.z, a1.w};
                float wr[8] = {w0.x, w0.y, w0.z, w0.w, w1.x, w1.y, w1.z, w1.w};
                #pragma unroll
                for (int r = 0; r < 8; ++r)
                    #pragma unroll
                    for (int c = 0; c < 8; ++c)
                        acc[r][c] = fmaf(a[r], wr[c], acc[r][c]);
            }
        }
    }

    float4 bv0 = *(const float4*)(bias + tx * 8);
    float4 bv1 = *(const float4*)(bias + tx * 8 + 4);
    float bb[8] = {bv0.x, bv0.y, bv0.z, bv0.w, bv1.x, bv1.y, bv1.z, bv1.w};
    #pragma unroll
    for (int r = 0; r < 8; ++r) {
        int grow = row0 + ty * 8 + r;
        if (grow < M) {
            float4 t0, t1;
            t0.x = fmaxf(acc[r][0] + bb[0], 0.f);
            t0.y = fmaxf(acc[r][1] + bb[1], 0.f);
            t0.z = fmaxf(acc[r][2] + bb[2], 0.f);
            t0.w = fmaxf(acc[r][3] + bb[3], 0.f);
            t1.x = fmaxf(acc[r][4] + bb[4], 0.f);
            t1.y = fmaxf(acc[r][5] + bb[5], 0.f);
            t1.z = fmaxf(acc[r][6] + bb[6], 0.f);
            t1.w = fmaxf(acc[r][7] + bb[7], 0.f);
            float4* yp0 = (float4*)(Y + (size_t)grow * D + tx * 8);
            float4* yp1 = (float4*)(Y + (size_t)grow * D + tx * 8 + 4);
            if (ACC) {
                float4 o0 = *yp0, o1 = *yp1;
                t0.x += o0.x; t0.y += o0.y; t0.z += o0.z; t0.w += o0.w;
                t1.x += o1.x; t1.y += o1.y; t1.z += o1.z; t1.w += o1.w;
            }
            *yp0 = t0;
            *yp1 = t1;
        }
    }
}

// ---------------- launch ----------------

extern "C" void kernel_launch(void* const* d_in, const int* in_sizes, int n_in,
                              void* d_out, int out_size, void* d_ws, size_t ws_size,
                              hipStream_t stream) {
    const float* h_station = (const float*)d_in[0];
    const float* h_feature = (const float*)d_in[1];
    const float* Wself     = (const float*)d_in[2];
    const float* Wneigh    = (const float*)d_in[3];
    const float* bias      = (const float*)d_in[4];
    const int* hf_src = (const int*)d_in[5];
    const int* hf_dst = (const int*)d_in[6];
    const int* tt_src = (const int*)d_in[7];
    const int* tt_dst = (const int*)d_in[8];

    const int NS = in_sizes[0] / D;
    const int E1 = in_sizes[5];
    const int E2 = in_sizes[7];

    // workspace carve-up
    char* ws = (char*)d_ws;
    size_t off = 0;
    auto alloc = [&](size_t bytes) -> void* {
        void* p = ws + off;
        off = (off + bytes + 255) & ~(size_t)255;
        return p;
    };
    float* n_buf  = (float*)alloc((size_t)NS * D * sizeof(float));
    float* h_buf  = (float*)alloc((size_t)NS * D * sizeof(float));
    int* rp_hf    = (int*)alloc((size_t)(NS + 1) * sizeof(int));
    int* col_hf   = (int*)alloc((size_t)E1 * sizeof(int));
    int* rp_tt    = (int*)alloc((size_t)(NS + 1) * sizeof(int));
    int* col_tt   = (int*)alloc((size_t)E2 * sizeof(int));
    int* deg_hf   = (int*)alloc((size_t)NS * sizeof(int));
    int* deg_tt   = (int*)alloc((size_t)NS * sizeof(int));
    int* cur_hf   = (int*)alloc((size_t)NS * sizeof(int));
    int* cur_tt   = (int*)alloc((size_t)NS * sizeof(int));

    const int tpb = 256;
    int gz = (NS + tpb - 1) / tpb;
    int ge = (max(E1, E2) + tpb - 1) / tpb;

    zero4_kernel<<<gz, tpb, 0, stream>>>(deg_hf, deg_tt, cur_hf, cur_tt, NS);
    count_both_kernel<<<ge, tpb, 0, stream>>>(hf_dst, tt_dst, deg_hf, deg_tt, E1, E2);
    scan2_kernel<<<1, 1024, 0, stream>>>(deg_hf, rp_hf, deg_tt, rp_tt, NS);
    fill_both_kernel<<<ge, tpb, 0, stream>>>(hf_src, hf_dst, rp_hf, cur_hf, col_hf,
                                             tt_src, tt_dst, rp_tt, cur_tt, col_tt, E1, E2);

    int gagg  = (NS * 64 + tpb - 1) / tpb;   // one wave per dst row
    int ggemm = (NS + 127) / 128;

    auto WS = [&](int l, int r) { return Wself  + (size_t)(l * 2 + r) * D * D; };
    auto WN = [&](int l, int r) { return Wneigh + (size_t)(l * 2 + r) * D * D; };
    auto BI = [&](int l, int r) { return bias   + (size_t)(l * 2 + r) * D; };

    float* out = (float*)d_out;

    // ---- layer 1 ----
    agg_mean_kernel<<<gagg, tpb, 0, stream>>>(h_feature, rp_hf, col_hf, n_buf, NS);
    sage_gemm_kernel<false><<<ggemm, tpb, 0, stream>>>(h_station, n_buf, WS(0,0), WN(0,0), BI(0,0), h_buf, NS);
    agg_mean_kernel<<<gagg, tpb, 0, stream>>>(h_station, rp_tt, col_tt, n_buf, NS);
    sage_gemm_kernel<true><<<ggemm, tpb, 0, stream>>>(h_station, n_buf, WS(0,1), WN(0,1), BI(0,1), h_buf, NS);

    // ---- layer 2 (in-place on h_buf: each block only reads/writes its own rows) ----
    agg_mean_kernel<<<gagg, tpb, 0, stream>>>(h_buf, rp_tt, col_tt, n_buf, NS);
    sage_gemm_kernel<false><<<ggemm, tpb, 0, stream>>>(h_buf, n_buf, WS(1,1), WN(1,1), BI(1,1), h_buf, NS);

    // ---- layer 3 ----
    agg_mean_kernel<<<gagg, tpb, 0, stream>>>(h_buf, rp_tt, col_tt, n_buf, NS);
    sage_gemm_kernel<false><<<ggemm, tpb, 0, stream>>>(h_buf, n_buf, WS(2,1), WN(2,1), BI(2,1), out, NS);
}

// Round 4
// 514.251 us; speedup vs baseline: 46.1187x; 1.2784x over previous
//
#include <hip/hip_runtime.h>

#define D 128

// ---------------- CSR build (both graphs fused) ----------------

__global__ void zero4_kernel(int* __restrict__ a, int* __restrict__ b,
                             int* __restrict__ c, int* __restrict__ d, int n) {
    int i = blockIdx.x * blockDim.x + threadIdx.x;
    if (i < n) { a[i] = 0; b[i] = 0; c[i] = 0; d[i] = 0; }
}

__global__ void count_both_kernel(const int* __restrict__ hf_dst, const int* __restrict__ tt_dst,
                                  int* __restrict__ deg_hf, int* __restrict__ deg_tt,
                                  int E1, int E2) {
    int i = blockIdx.x * blockDim.x + threadIdx.x;
    if (i < E1) atomicAdd(&deg_hf[hf_dst[i]], 1);
    if (i < E2) atomicAdd(&deg_tt[tt_dst[i]], 1);
}

// ---- multi-block scan (round 3: single-block scan2 was 153us at 0.18% occupancy) ----
// level 1: 1024 elems per block (256 thr x int4), block-local exclusive scan + block sums
#define SCAN_EPB 1024

__global__ __launch_bounds__(256) void scan_blocks_kernel(
    const int* __restrict__ deg_hf, int* __restrict__ rp_hf, int* __restrict__ bs_hf,
    const int* __restrict__ deg_tt, int* __restrict__ rp_tt, int* __restrict__ bs_tt,
    int n, int nb)
{
    int gid = blockIdx.x;
    const int* deg; int* rp; int* bs; int b;
    if (gid < nb) { deg = deg_hf; rp = rp_hf; bs = bs_hf; b = gid; }
    else         { deg = deg_tt; rp = rp_tt; bs = bs_tt; b = gid - nb; }
    int t = threadIdx.x;
    int i0 = b * SCAN_EPB + t * 4;
    int4 v = make_int4(0, 0, 0, 0);
    if (i0 + 3 < n) v = *(const int4*)(deg + i0);
    else {
        if (i0 + 0 < n) v.x = deg[i0 + 0];
        if (i0 + 1 < n) v.y = deg[i0 + 1];
        if (i0 + 2 < n) v.z = deg[i0 + 2];
        if (i0 + 3 < n) v.w = deg[i0 + 3];
    }
    __shared__ int sm[256];
    sm[t] = v.x + v.y + v.z + v.w;
    __syncthreads();
    for (int off = 1; off < 256; off <<= 1) {
        int x = (t >= off) ? sm[t - off] : 0;
        __syncthreads();
        sm[t] += x;
        __syncthreads();
    }
    int excl = (t > 0) ? sm[t - 1] : 0;
    if (i0 + 0 < n) rp[i0 + 0] = excl;
    if (i0 + 1 < n) rp[i0 + 1] = excl + v.x;
    if (i0 + 2 < n) rp[i0 + 2] = excl + v.x + v.y;
    if (i0 + 3 < n) rp[i0 + 3] = excl + v.x + v.y + v.z;
    if (t == 255) bs[b] = sm[255];
}

// level 2: add block offsets (each thread wave-reduces the <=64 block sums); rp[n] = E
__global__ __launch_bounds__(256) void scan_offsets_kernel(
    int* __restrict__ rp_hf, const int* __restrict__ bs_hf,
    int* __restrict__ rp_tt, const int* __restrict__ bs_tt,
    int n, int nb, int E1, int E2)
{
    int gid = blockIdx.x;
    int* rp; const int* bs; int b; int E;
    if (gid < nb) { rp = rp_hf; bs = bs_hf; b = gid; E = E1; }
    else         { rp = rp_tt; bs = bs_tt; b = gid - nb; E = E2; }
    int t = threadIdx.x;
    int lane = t & 63;
    int partial = 0;
    for (int i = lane; i < b; i += 64) partial += bs[i];
    #pragma unroll
    for (int off = 32; off; off >>= 1) partial += __shfl_xor(partial, off);
    if (b == 0 && t == 0) rp[n] = E;
    if (partial == 0) return;   // block 0 (and empty prefixes): nothing to add
    int i0 = b * SCAN_EPB + t * 4;
    if (i0 + 0 < n) rp[i0 + 0] += partial;
    if (i0 + 1 < n) rp[i0 + 1] += partial;
    if (i0 + 2 < n) rp[i0 + 2] += partial;
    if (i0 + 3 < n) rp[i0 + 3] += partial;
}

__global__ void fill_both_kernel(
    const int* __restrict__ hf_src, const int* __restrict__ hf_dst,
    const int* __restrict__ rp_hf, int* __restrict__ cur_hf, int* __restrict__ col_hf,
    const int* __restrict__ tt_src, const int* __restrict__ tt_dst,
    const int* __restrict__ rp_tt, int* __restrict__ cur_tt, int* __restrict__ col_tt,
    int E1, int E2) {
    int i = blockIdx.x * blockDim.x + threadIdx.x;
    if (i < E1) {
        int d = hf_dst[i];
        int pos = atomicAdd(&cur_hf[d], 1);
        col_hf[rp_hf[d] + pos] = hf_src[i];
    }
    if (i < E2) {
        int d = tt_dst[i];
        int pos = atomicAdd(&cur_tt[d], 1);
        col_tt[rp_tt[d] + pos] = tt_src[i];
    }
}

// ---------------- segment mean (one wave per destination row) ----------------
// coalesced index preload + shfl broadcast, 4-wide unrolled gathers (round 2 fix).

__global__ __launch_bounds__(256) void agg_mean_kernel(
    const float* __restrict__ hsrc, const int* __restrict__ rowptr,
    const int* __restrict__ col, float* __restrict__ out, int ndst) {
    int w = (blockIdx.x * blockDim.x + threadIdx.x) >> 6;   // wave id = dst row
    int lane = threadIdx.x & 63;
    if (w >= ndst) return;
    int beg = rowptr[w];
    int end = rowptr[w + 1];
    int deg = end - beg;
    float ax0 = 0.f, ay0 = 0.f, ax1 = 0.f, ay1 = 0.f;
    float ax2 = 0.f, ay2 = 0.f, ax3 = 0.f, ay3 = 0.f;
    const float* base = hsrc + lane * 2;
    for (int b = beg; b < end; b += 64) {
        int n = min(64, end - b);
        int myidx = (lane < n) ? col[b + lane] : 0;
        int j = 0;
        for (; j + 4 <= n; j += 4) {
            int s0 = __shfl(myidx, j);
            int s1 = __shfl(myidx, j + 1);
            int s2 = __shfl(myidx, j + 2);
            int s3 = __shfl(myidx, j + 3);
            float2 v0 = *(const float2*)(base + (size_t)s0 * D);
            float2 v1 = *(const float2*)(base + (size_t)s1 * D);
            float2 v2 = *(const float2*)(base + (size_t)s2 * D);
            float2 v3 = *(const float2*)(base + (size_t)s3 * D);
            ax0 += v0.x; ay0 += v0.y;
            ax1 += v1.x; ay1 += v1.y;
            ax2 += v2.x; ay2 += v2.y;
            ax3 += v3.x; ay3 += v3.y;
        }
        for (; j < n; ++j) {
            int s0 = __shfl(myidx, j);
            float2 v0 = *(const float2*)(base + (size_t)s0 * D);
            ax0 += v0.x; ay0 += v0.y;
        }
    }
    float inv = 1.0f / fmaxf((float)deg, 1.0f);
    float2 r;
    r.x = ((ax0 + ax1) + (ax2 + ax3)) * inv;
    r.y = ((ay0 + ay1) + (ay2 + ay3)) * inv;
    *(float2*)(out + (size_t)w * D + lane * 2) = r;
}

// ---------------- fused SAGE layer: Y = relu(A@W1 + B@W2 + bias) [+= if ACC] ----------------
// BM=128, BN=128, BK=16. 256 threads; 8x8 micro-tile (64 FMA per 4 ds_read_b128).
// Tile loops pinned to unroll 1 — full unrolling spilled acc to scratch in round 1.

template<bool ACC>
__global__ __launch_bounds__(256) void sage_gemm_kernel(
    const float* __restrict__ A, const float* __restrict__ B,
    const float* __restrict__ W1, const float* __restrict__ W2,
    const float* __restrict__ bias, float* __restrict__ Y, int M)
{
    __shared__ float As[16][128];
    __shared__ float Ws[16][128];
    int tid = threadIdx.x;
    int tx = tid & 15;        // col group: cols tx*8 .. tx*8+7
    int ty = tid >> 4;        // row group: rows ty*8 .. ty*8+7
    int row0 = blockIdx.x * 128;

    int la_row = tid >> 1;          // 0..127
    int la_k   = (tid & 1) * 8;     // 0 or 8
    int lw_n   = (tid & 31) * 4;    // 0..124
    int lw_k   = tid >> 5;          // 0..7

    float acc[8][8];
    #pragma unroll
    for (int r = 0; r < 8; ++r)
        #pragma unroll
        for (int c = 0; c < 8; ++c) acc[r][c] = 0.f;

    #pragma unroll 1
    for (int half = 0; half < 2; ++half) {
        const float* Ain = half ? B : A;
        const float* Win = half ? W2 : W1;
        #pragma unroll 1
        for (int k0 = 0; k0 < 128; k0 += 16) {
            int grow = row0 + la_row;
            float4 av0 = make_float4(0.f, 0.f, 0.f, 0.f);
            float4 av1 = make_float4(0.f, 0.f, 0.f, 0.f);
            if (grow < M) {
                av0 = *(const float4*)(Ain + (size_t)grow * D + k0 + la_k);
                av1 = *(const float4*)(Ain + (size_t)grow * D + k0 + la_k + 4);
            }
            float4 wv0 = *(const float4*)(Win + (size_t)(k0 + lw_k) * D + lw_n);
            float4 wv1 = *(const float4*)(Win + (size_t)(k0 + lw_k + 8) * D + lw_n);
            __syncthreads();
            As[la_k + 0][la_row] = av0.x;
            As[la_k + 1][la_row] = av0.y;
            As[la_k + 2][la_row] = av0.z;
            As[la_k + 3][la_row] = av0.w;
            As[la_k + 4][la_row] = av1.x;
            As[la_k + 5][la_row] = av1.y;
            As[la_k + 6][la_row] = av1.z;
            As[la_k + 7][la_row] = av1.w;
            *(float4*)&Ws[lw_k][lw_n]     = wv0;
            *(float4*)&Ws[lw_k + 8][lw_n] = wv1;
            __syncthreads();
            #pragma unroll
            for (int k = 0; k < 16; ++k) {
                float4 w0 = *(const float4*)&Ws[k][tx * 8];
                float4 w1 = *(const float4*)&Ws[k][tx * 8 + 4];
                float4 a0 = *(const float4*)&As[k][ty * 8];
                float4 a1 = *(const float4*)&As[k][ty * 8 + 4];
                float a[8] = {a0.x, a0.y, a0.z, a0.w, a1.x, a1.y, a1.z, a1.w};
                float wr[8] = {w0.x, w0.y, w0.z, w0.w, w1.x, w1.y, w1.z, w1.w};
                #pragma unroll
                for (int r = 0; r < 8; ++r)
                    #pragma unroll
                    for (int c = 0; c < 8; ++c)
                        acc[r][c] = fmaf(a[r], wr[c], acc[r][c]);
            }
        }
    }

    float4 bv0 = *(const float4*)(bias + tx * 8);
    float4 bv1 = *(const float4*)(bias + tx * 8 + 4);
    float bb[8] = {bv0.x, bv0.y, bv0.z, bv0.w, bv1.x, bv1.y, bv1.z, bv1.w};
    #pragma unroll
    for (int r = 0; r < 8; ++r) {
        int grow = row0 + ty * 8 + r;
        if (grow < M) {
            float4 t0, t1;
            t0.x = fmaxf(acc[r][0] + bb[0], 0.f);
            t0.y = fmaxf(acc[r][1] + bb[1], 0.f);
            t0.z = fmaxf(acc[r][2] + bb[2], 0.f);
            t0.w = fmaxf(acc[r][3] + bb[3], 0.f);
            t1.x = fmaxf(acc[r][4] + bb[4], 0.f);
            t1.y = fmaxf(acc[r][5] + bb[5], 0.f);
            t1.z = fmaxf(acc[r][6] + bb[6], 0.f);
            t1.w = fmaxf(acc[r][7] + bb[7], 0.f);
            float4* yp0 = (float4*)(Y + (size_t)grow * D + tx * 8);
            float4* yp1 = (float4*)(Y + (size_t)grow * D + tx * 8 + 4);
            if (ACC) {
                float4 o0 = *yp0, o1 = *yp1;
                t0.x += o0.x; t0.y += o0.y; t0.z += o0.z; t0.w += o0.w;
                t1.x += o1.x; t1.y += o1.y; t1.z += o1.z; t1.w += o1.w;
            }
            *yp0 = t0;
            *yp1 = t1;
        }
    }
}

// ---------------- launch ----------------

extern "C" void kernel_launch(void* const* d_in, const int* in_sizes, int n_in,
                              void* d_out, int out_size, void* d_ws, size_t ws_size,
                              hipStream_t stream) {
    const float* h_station = (const float*)d_in[0];
    const float* h_feature = (const float*)d_in[1];
    const float* Wself     = (const float*)d_in[2];
    const float* Wneigh    = (const float*)d_in[3];
    const float* bias      = (const float*)d_in[4];
    const int* hf_src = (const int*)d_in[5];
    const int* hf_dst = (const int*)d_in[6];
    const int* tt_src = (const int*)d_in[7];
    const int* tt_dst = (const int*)d_in[8];

    const int NS = in_sizes[0] / D;
    const int E1 = in_sizes[5];
    const int E2 = in_sizes[7];

    // workspace carve-up
    char* ws = (char*)d_ws;
    size_t off = 0;
    auto alloc = [&](size_t bytes) -> void* {
        void* p = ws + off;
        off = (off + bytes + 255) & ~(size_t)255;
        return p;
    };
    float* n_buf  = (float*)alloc((size_t)NS * D * sizeof(float));
    float* h_buf  = (float*)alloc((size_t)NS * D * sizeof(float));
    int* rp_hf    = (int*)alloc((size_t)(NS + 1) * sizeof(int));
    int* col_hf   = (int*)alloc((size_t)E1 * sizeof(int));
    int* rp_tt    = (int*)alloc((size_t)(NS + 1) * sizeof(int));
    int* col_tt   = (int*)alloc((size_t)E2 * sizeof(int));
    int* deg_hf   = (int*)alloc((size_t)NS * sizeof(int));
    int* deg_tt   = (int*)alloc((size_t)NS * sizeof(int));
    int* cur_hf   = (int*)alloc((size_t)NS * sizeof(int));
    int* cur_tt   = (int*)alloc((size_t)NS * sizeof(int));
    int  nb       = (NS + SCAN_EPB - 1) / SCAN_EPB;
    int* bs_hf    = (int*)alloc((size_t)nb * sizeof(int));
    int* bs_tt    = (int*)alloc((size_t)nb * sizeof(int));

    const int tpb = 256;
    int gz = (NS + tpb - 1) / tpb;
    int ge = (max(E1, E2) + tpb - 1) / tpb;

    zero4_kernel<<<gz, tpb, 0, stream>>>(deg_hf, deg_tt, cur_hf, cur_tt, NS);
    count_both_kernel<<<ge, tpb, 0, stream>>>(hf_dst, tt_dst, deg_hf, deg_tt, E1, E2);
    scan_blocks_kernel<<<2 * nb, tpb, 0, stream>>>(deg_hf, rp_hf, bs_hf,
                                                   deg_tt, rp_tt, bs_tt, NS, nb);
    scan_offsets_kernel<<<2 * nb, tpb, 0, stream>>>(rp_hf, bs_hf, rp_tt, bs_tt,
                                                    NS, nb, E1, E2);
    fill_both_kernel<<<ge, tpb, 0, stream>>>(hf_src, hf_dst, rp_hf, cur_hf, col_hf,
                                             tt_src, tt_dst, rp_tt, cur_tt, col_tt, E1, E2);

    int gagg  = (NS * 64 + tpb - 1) / tpb;   // one wave per dst row
    int ggemm = (NS + 127) / 128;

    auto WS = [&](int l, int r) { return Wself  + (size_t)(l * 2 + r) * D * D; };
    auto WN = [&](int l, int r) { return Wneigh + (size_t)(l * 2 + r) * D * D; };
    auto BI = [&](int l, int r) { return bias   + (size_t)(l * 2 + r) * D; };

    float* out = (float*)d_out;

    // ---- layer 1 ----
    agg_mean_kernel<<<gagg, tpb, 0, stream>>>(h_feature, rp_hf, col_hf, n_buf, NS);
    sage_gemm_kernel<false><<<ggemm, tpb, 0, stream>>>(h_station, n_buf, WS(0,0), WN(0,0), BI(0,0), h_buf, NS);
    agg_mean_kernel<<<gagg, tpb, 0, stream>>>(h_station, rp_tt, col_tt, n_buf, NS);
    sage_gemm_kernel<true><<<ggemm, tpb, 0, stream>>>(h_station, n_buf, WS(0,1), WN(0,1), BI(0,1), h_buf, NS);

    // ---- layer 2 (in-place on h_buf: each block only reads/writes its own rows) ----
    agg_mean_kernel<<<gagg, tpb, 0, stream>>>(h_buf, rp_tt, col_tt, n_buf, NS);
    sage_gemm_kernel<false><<<ggemm, tpb, 0, stream>>>(h_buf, n_buf, WS(1,1), WN(1,1), BI(1,1), h_buf, NS);

    // ---- layer 3 ----
    agg_mean_kernel<<<gagg, tpb, 0, stream>>>(h_buf, rp_tt, col_tt, n_buf, NS);
    sage_gemm_kernel<false><<<ggemm, tpb, 0, stream>>>(h_buf, n_buf, WS(2,1), WN(2,1), BI(2,1), out, NS);
}

// Round 5
// 476.929 us; speedup vs baseline: 49.7277x; 1.0783x over previous
//
#include <hip/hip_runtime.h>

#define D 128

// ---------------- CSR build (both graphs fused) ----------------
// Round-4: fill_both was 85us — 1.2M device-scope atomics (cursor) + scattered
// stores, WRITE_SIZE 84MB. Fix: count's atomicAdd already yields each edge's
// slot (old value) — store it as ushort rank[], fill becomes atomic-free.

__global__ void zero2_kernel(int* __restrict__ a, int* __restrict__ b, int n) {
    int i = blockIdx.x * blockDim.x + threadIdx.x;
    if (i < n) { a[i] = 0; b[i] = 0; }
}

__global__ void count_rank_kernel(const int* __restrict__ hf_dst, const int* __restrict__ tt_dst,
                                  int* __restrict__ deg_hf, int* __restrict__ deg_tt,
                                  unsigned short* __restrict__ rank_hf,
                                  unsigned short* __restrict__ rank_tt,
                                  int E1, int E2) {
    int i = blockIdx.x * blockDim.x + threadIdx.x;
    if (i < E1) {
        int r = atomicAdd(&deg_hf[hf_dst[i]], 1);
        rank_hf[i] = (unsigned short)r;
    }
    if (i < E2) {
        int r = atomicAdd(&deg_tt[tt_dst[i]], 1);
        rank_tt[i] = (unsigned short)r;
    }
}

// ---- multi-block scan (round 3: single-block scan was 153us at 0.18% occupancy) ----
#define SCAN_EPB 1024

__global__ __launch_bounds__(256) void scan_blocks_kernel(
    const int* __restrict__ deg_hf, int* __restrict__ rp_hf, int* __restrict__ bs_hf,
    const int* __restrict__ deg_tt, int* __restrict__ rp_tt, int* __restrict__ bs_tt,
    int n, int nb)
{
    int gid = blockIdx.x;
    const int* deg; int* rp; int* bs; int b;
    if (gid < nb) { deg = deg_hf; rp = rp_hf; bs = bs_hf; b = gid; }
    else         { deg = deg_tt; rp = rp_tt; bs = bs_tt; b = gid - nb; }
    int t = threadIdx.x;
    int i0 = b * SCAN_EPB + t * 4;
    int4 v = make_int4(0, 0, 0, 0);
    if (i0 + 3 < n) v = *(const int4*)(deg + i0);
    else {
        if (i0 + 0 < n) v.x = deg[i0 + 0];
        if (i0 + 1 < n) v.y = deg[i0 + 1];
        if (i0 + 2 < n) v.z = deg[i0 + 2];
        if (i0 + 3 < n) v.w = deg[i0 + 3];
    }
    __shared__ int sm[256];
    sm[t] = v.x + v.y + v.z + v.w;
    __syncthreads();
    for (int off = 1; off < 256; off <<= 1) {
        int x = (t >= off) ? sm[t - off] : 0;
        __syncthreads();
        sm[t] += x;
        __syncthreads();
    }
    int excl = (t > 0) ? sm[t - 1] : 0;
    if (i0 + 0 < n) rp[i0 + 0] = excl;
    if (i0 + 1 < n) rp[i0 + 1] = excl + v.x;
    if (i0 + 2 < n) rp[i0 + 2] = excl + v.x + v.y;
    if (i0 + 3 < n) rp[i0 + 3] = excl + v.x + v.y + v.z;
    if (t == 255) bs[b] = sm[255];
}

__global__ __launch_bounds__(256) void scan_offsets_kernel(
    int* __restrict__ rp_hf, const int* __restrict__ bs_hf,
    int* __restrict__ rp_tt, const int* __restrict__ bs_tt,
    int n, int nb, int E1, int E2)
{
    int gid = blockIdx.x;
    int* rp; const int* bs; int b; int E;
    if (gid < nb) { rp = rp_hf; bs = bs_hf; b = gid; E = E1; }
    else         { rp = rp_tt; bs = bs_tt; b = gid - nb; E = E2; }
    int t = threadIdx.x;
    int lane = t & 63;
    int partial = 0;
    for (int i = lane; i < b; i += 64) partial += bs[i];
    #pragma unroll
    for (int off = 32; off; off >>= 1) partial += __shfl_xor(partial, off);
    if (b == 0 && t == 0) rp[n] = E;
    if (partial == 0) return;
    int i0 = b * SCAN_EPB + t * 4;
    if (i0 + 0 < n) rp[i0 + 0] += partial;
    if (i0 + 1 < n) rp[i0 + 1] += partial;
    if (i0 + 2 < n) rp[i0 + 2] += partial;
    if (i0 + 3 < n) rp[i0 + 3] += partial;
}

// atomic-free fill: col[rp[dst] + rank] = src
__global__ void fill_both_kernel(
    const int* __restrict__ hf_src, const int* __restrict__ hf_dst,
    const unsigned short* __restrict__ rank_hf,
    const int* __restrict__ rp_hf, int* __restrict__ col_hf,
    const int* __restrict__ tt_src, const int* __restrict__ tt_dst,
    const unsigned short* __restrict__ rank_tt,
    const int* __restrict__ rp_tt, int* __restrict__ col_tt,
    int E1, int E2) {
    int i = blockIdx.x * blockDim.x + threadIdx.x;
    if (i < E1) {
        int d = hf_dst[i];
        col_hf[rp_hf[d] + rank_hf[i]] = hf_src[i];
    }
    if (i < E2) {
        int d = tt_dst[i];
        col_tt[rp_tt[d] + rank_tt[i]] = tt_src[i];
    }
}

// ---------------- segment mean (one wave per destination row) ----------------
// Latency-bound on random L3 row gathers -> 8 independent gather chains in flight.

__global__ __launch_bounds__(256) void agg_mean_kernel(
    const float* __restrict__ hsrc, const int* __restrict__ rowptr,
    const int* __restrict__ col, float* __restrict__ out, int ndst) {
    int w = (blockIdx.x * blockDim.x + threadIdx.x) >> 6;   // wave id = dst row
    int lane = threadIdx.x & 63;
    if (w >= ndst) return;
    int beg = rowptr[w];
    int end = rowptr[w + 1];
    int deg = end - beg;
    float ax[8], ay[8];
    #pragma unroll
    for (int u = 0; u < 8; ++u) { ax[u] = 0.f; ay[u] = 0.f; }
    const float* base = hsrc + lane * 2;
    for (int b = beg; b < end; b += 64) {
        int n = min(64, end - b);
        int myidx = (lane < n) ? col[b + lane] : 0;
        int j = 0;
        for (; j + 8 <= n; j += 8) {
            int s[8];
            #pragma unroll
            for (int u = 0; u < 8; ++u) s[u] = __shfl(myidx, j + u);
            float2 v[8];
            #pragma unroll
            for (int u = 0; u < 8; ++u) v[u] = *(const float2*)(base + (size_t)s[u] * D);
            #pragma unroll
            for (int u = 0; u < 8; ++u) { ax[u] += v[u].x; ay[u] += v[u].y; }
        }
        for (; j + 4 <= n; j += 4) {
            int s[4];
            #pragma unroll
            for (int u = 0; u < 4; ++u) s[u] = __shfl(myidx, j + u);
            float2 v[4];
            #pragma unroll
            for (int u = 0; u < 4; ++u) v[u] = *(const float2*)(base + (size_t)s[u] * D);
            #pragma unroll
            for (int u = 0; u < 4; ++u) { ax[u] += v[u].x; ay[u] += v[u].y; }
        }
        for (; j < n; ++j) {
            int s0 = __shfl(myidx, j);
            float2 v0 = *(const float2*)(base + (size_t)s0 * D);
            ax[0] += v0.x; ay[0] += v0.y;
        }
    }
    float inv = 1.0f / fmaxf((float)deg, 1.0f);
    float sx = ((ax[0] + ax[1]) + (ax[2] + ax[3])) + ((ax[4] + ax[5]) + (ax[6] + ax[7]));
    float sy = ((ay[0] + ay[1]) + (ay[2] + ay[3])) + ((ay[4] + ay[5]) + (ay[6] + ay[7]));
    float2 r; r.x = sx * inv; r.y = sy * inv;
    *(float2*)(out + (size_t)w * D + lane * 2) = r;
}

// ---------------- fused SAGE layer: Y = relu(A@W1 + B@W2 + bias) [+= if ACC] ----------------
// BM=128, BN=128, BK=16. 256 threads; 8x8 micro-tile.
// Tile loops pinned to unroll 1 — full unrolling spilled acc to scratch in round 1.

template<bool ACC>
__global__ __launch_bounds__(256) void sage_gemm_kernel(
    const float* __restrict__ A, const float* __restrict__ B,
    const float* __restrict__ W1, const float* __restrict__ W2,
    const float* __restrict__ bias, float* __restrict__ Y, int M)
{
    __shared__ float As[16][128];
    __shared__ float Ws[16][128];
    int tid = threadIdx.x;
    int tx = tid & 15;
    int ty = tid >> 4;
    int row0 = blockIdx.x * 128;

    int la_row = tid >> 1;
    int la_k   = (tid & 1) * 8;
    int lw_n   = (tid & 31) * 4;
    int lw_k   = tid >> 5;

    float acc[8][8];
    #pragma unroll
    for (int r = 0; r < 8; ++r)
        #pragma unroll
        for (int c = 0; c < 8; ++c) acc[r][c] = 0.f;

    #pragma unroll 1
    for (int half = 0; half < 2; ++half) {
        const float* Ain = half ? B : A;
        const float* Win = half ? W2 : W1;
        #pragma unroll 1
        for (int k0 = 0; k0 < 128; k0 += 16) {
            int grow = row0 + la_row;
            float4 av0 = make_float4(0.f, 0.f, 0.f, 0.f);
            float4 av1 = make_float4(0.f, 0.f, 0.f, 0.f);
            if (grow < M) {
                av0 = *(const float4*)(Ain + (size_t)grow * D + k0 + la_k);
                av1 = *(const float4*)(Ain + (size_t)grow * D + k0 + la_k + 4);
            }
            float4 wv0 = *(const float4*)(Win + (size_t)(k0 + lw_k) * D + lw_n);
            float4 wv1 = *(const float4*)(Win + (size_t)(k0 + lw_k + 8) * D + lw_n);
            __syncthreads();
            As[la_k + 0][la_row] = av0.x;
            As[la_k + 1][la_row] = av0.y;
            As[la_k + 2][la_row] = av0.z;
            As[la_k + 3][la_row] = av0.w;
            As[la_k + 4][la_row] = av1.x;
            As[la_k + 5][la_row] = av1.y;
            As[la_k + 6][la_row] = av1.z;
            As[la_k + 7][la_row] = av1.w;
            *(float4*)&Ws[lw_k][lw_n]     = wv0;
            *(float4*)&Ws[lw_k + 8][lw_n] = wv1;
            __syncthreads();
            #pragma unroll
            for (int k = 0; k < 16; ++k) {
                float4 w0 = *(const float4*)&Ws[k][tx * 8];
                float4 w1 = *(const float4*)&Ws[k][tx * 8 + 4];
                float4 a0 = *(const float4*)&As[k][ty * 8];
                float4 a1 = *(const float4*)&As[k][ty * 8 + 4];
                float a[8] = {a0.x, a0.y, a0.z, a0.w, a1.x, a1.y, a1.z, a1.w};
                float wr[8] = {w0.x, w0.y, w0.z, w0.w, w1.x, w1.y, w1.z, w1.w};
                #pragma unroll
                for (int r = 0; r < 8; ++r)
                    #pragma unroll
                    for (int c = 0; c < 8; ++c)
                        acc[r][c] = fmaf(a[r], wr[c], acc[r][c]);
            }
        }
    }

    float4 bv0 = *(const float4*)(bias + tx * 8);
    float4 bv1 = *(const float4*)(bias + tx * 8 + 4);
    float bb[8] = {bv0.x, bv0.y, bv0.z, bv0.w, bv1.x, bv1.y, bv1.z, bv1.w};
    #pragma unroll
    for (int r = 0; r < 8; ++r) {
        int grow = row0 + ty * 8 + r;
        if (grow < M) {
            float4 t0, t1;
            t0.x = fmaxf(acc[r][0] + bb[0], 0.f);
            t0.y = fmaxf(acc[r][1] + bb[1], 0.f);
            t0.z = fmaxf(acc[r][2] + bb[2], 0.f);
            t0.w = fmaxf(acc[r][3] + bb[3], 0.f);
            t1.x = fmaxf(acc[r][4] + bb[4], 0.f);
            t1.y = fmaxf(acc[r][5] + bb[5], 0.f);
            t1.z = fmaxf(acc[r][6] + bb[6], 0.f);
            t1.w = fmaxf(acc[r][7] + bb[7], 0.f);
            float4* yp0 = (float4*)(Y + (size_t)grow * D + tx * 8);
            float4* yp1 = (float4*)(Y + (size_t)grow * D + tx * 8 + 4);
            if (ACC) {
                float4 o0 = *yp0, o1 = *yp1;
                t0.x += o0.x; t0.y += o0.y; t0.z += o0.z; t0.w += o0.w;
                t1.x += o1.x; t1.y += o1.y; t1.z += o1.z; t1.w += o1.w;
            }
            *yp0 = t0;
            *yp1 = t1;
        }
    }
}

// ---------------- launch ----------------

extern "C" void kernel_launch(void* const* d_in, const int* in_sizes, int n_in,
                              void* d_out, int out_size, void* d_ws, size_t ws_size,
                              hipStream_t stream) {
    const float* h_station = (const float*)d_in[0];
    const float* h_feature = (const float*)d_in[1];
    const float* Wself     = (const float*)d_in[2];
    const float* Wneigh    = (const float*)d_in[3];
    const float* bias      = (const float*)d_in[4];
    const int* hf_src = (const int*)d_in[5];
    const int* hf_dst = (const int*)d_in[6];
    const int* tt_src = (const int*)d_in[7];
    const int* tt_dst = (const int*)d_in[8];

    const int NS = in_sizes[0] / D;
    const int E1 = in_sizes[5];
    const int E2 = in_sizes[7];

    // workspace carve-up
    char* ws = (char*)d_ws;
    size_t off = 0;
    auto alloc = [&](size_t bytes) -> void* {
        void* p = ws + off;
        off = (off + bytes + 255) & ~(size_t)255;
        return p;
    };
    float* n_buf  = (float*)alloc((size_t)NS * D * sizeof(float));
    float* h_buf  = (float*)alloc((size_t)NS * D * sizeof(float));
    int* rp_hf    = (int*)alloc((size_t)(NS + 1) * sizeof(int));
    int* col_hf   = (int*)alloc((size_t)E1 * sizeof(int));
    int* rp_tt    = (int*)alloc((size_t)(NS + 1) * sizeof(int));
    int* col_tt   = (int*)alloc((size_t)E2 * sizeof(int));
    int* deg_hf   = (int*)alloc((size_t)NS * sizeof(int));
    int* deg_tt   = (int*)alloc((size_t)NS * sizeof(int));
    unsigned short* rank_hf = (unsigned short*)alloc((size_t)E1 * sizeof(unsigned short));
    unsigned short* rank_tt = (unsigned short*)alloc((size_t)E2 * sizeof(unsigned short));
    int  nb       = (NS + SCAN_EPB - 1) / SCAN_EPB;
    int* bs_hf    = (int*)alloc((size_t)nb * sizeof(int));
    int* bs_tt    = (int*)alloc((size_t)nb * sizeof(int));

    const int tpb = 256;
    int gz = (NS + tpb - 1) / tpb;
    int ge = (max(E1, E2) + tpb - 1) / tpb;

    zero2_kernel<<<gz, tpb, 0, stream>>>(deg_hf, deg_tt, NS);
    count_rank_kernel<<<ge, tpb, 0, stream>>>(hf_dst, tt_dst, deg_hf, deg_tt,
                                              rank_hf, rank_tt, E1, E2);
    scan_blocks_kernel<<<2 * nb, tpb, 0, stream>>>(deg_hf, rp_hf, bs_hf,
                                                   deg_tt, rp_tt, bs_tt, NS, nb);
    scan_offsets_kernel<<<2 * nb, tpb, 0, stream>>>(rp_hf, bs_hf, rp_tt, bs_tt,
                                                    NS, nb, E1, E2);
    fill_both_kernel<<<ge, tpb, 0, stream>>>(hf_src, hf_dst, rank_hf, rp_hf, col_hf,
                                             tt_src, tt_dst, rank_tt, rp_tt, col_tt, E1, E2);

    int gagg  = (NS * 64 + tpb - 1) / tpb;   // one wave per dst row
    int ggemm = (NS + 127) / 128;

    auto WS = [&](int l, int r) { return Wself  + (size_t)(l * 2 + r) * D * D; };
    auto WN = [&](int l, int r) { return Wneigh + (size_t)(l * 2 + r) * D * D; };
    auto BI = [&](int l, int r) { return bias   + (size_t)(l * 2 + r) * D; };

    float* out = (float*)d_out;

    // ---- layer 1 ----
    agg_mean_kernel<<<gagg, tpb, 0, stream>>>(h_feature, rp_hf, col_hf, n_buf, NS);
    sage_gemm_kernel<false><<<ggemm, tpb, 0, stream>>>(h_station, n_buf, WS(0,0), WN(0,0), BI(0,0), h_buf, NS);
    agg_mean_kernel<<<gagg, tpb, 0, stream>>>(h_station, rp_tt, col_tt, n_buf, NS);
    sage_gemm_kernel<true><<<ggemm, tpb, 0, stream>>>(h_station, n_buf, WS(0,1), WN(0,1), BI(0,1), h_buf, NS);

    // ---- layer 2 (in-place on h_buf: each block only reads/writes its own rows) ----
    agg_mean_kernel<<<gagg, tpb, 0, stream>>>(h_buf, rp_tt, col_tt, n_buf, NS);
    sage_gemm_kernel<false><<<ggemm, tpb, 0, stream>>>(h_buf, n_buf, WS(1,1), WN(1,1), BI(1,1), h_buf, NS);

    // ---- layer 3 ----
    agg_mean_kernel<<<gagg, tpb, 0, stream>>>(h_buf, rp_tt, col_tt, n_buf, NS);
    sage_gemm_kernel<false><<<ggemm, tpb, 0, stream>>>(h_buf, n_buf, WS(2,1), WN(2,1), BI(2,1), out, NS);
}

// Round 6
// 380.520 us; speedup vs baseline: 62.3269x; 1.2534x over previous
//
#include <hip/hip_runtime.h>

#define D 128

typedef __attribute__((ext_vector_type(8)))  short s16x8;
typedef __attribute__((ext_vector_type(4)))  short s16x4;
typedef __attribute__((ext_vector_type(16))) float f32x16;

static __device__ __forceinline__ unsigned short f2bf(float x) {
    unsigned u = __builtin_bit_cast(unsigned, x);
    unsigned r = (u + 0x7FFF + ((u >> 16) & 1)) >> 16;   // RNE
    return (unsigned short)r;
}
static __device__ __forceinline__ float bf2f(unsigned short h) {
    unsigned u = ((unsigned)h) << 16;
    return __builtin_bit_cast(float, u);
}

// ---------------- CSR build (both graphs fused) ----------------

__global__ void zero2_kernel(int* __restrict__ a, int* __restrict__ b, int n) {
    int i = blockIdx.x * blockDim.x + threadIdx.x;
    if (i < n) { a[i] = 0; b[i] = 0; }
}

__global__ void count_rank_kernel(const int* __restrict__ hf_dst, const int* __restrict__ tt_dst,
                                  int* __restrict__ deg_hf, int* __restrict__ deg_tt,
                                  unsigned short* __restrict__ rank_hf,
                                  unsigned short* __restrict__ rank_tt,
                                  int E1, int E2) {
    int i = blockIdx.x * blockDim.x + threadIdx.x;
    if (i < E1) {
        int r = atomicAdd(&deg_hf[hf_dst[i]], 1);
        rank_hf[i] = (unsigned short)r;
    }
    if (i < E2) {
        int r = atomicAdd(&deg_tt[tt_dst[i]], 1);
        rank_tt[i] = (unsigned short)r;
    }
}

#define SCAN_EPB 1024

__global__ __launch_bounds__(256) void scan_blocks_kernel(
    const int* __restrict__ deg_hf, int* __restrict__ rp_hf, int* __restrict__ bs_hf,
    const int* __restrict__ deg_tt, int* __restrict__ rp_tt, int* __restrict__ bs_tt,
    int n, int nb)
{
    int gid = blockIdx.x;
    const int* deg; int* rp; int* bs; int b;
    if (gid < nb) { deg = deg_hf; rp = rp_hf; bs = bs_hf; b = gid; }
    else         { deg = deg_tt; rp = rp_tt; bs = bs_tt; b = gid - nb; }
    int t = threadIdx.x;
    int i0 = b * SCAN_EPB + t * 4;
    int4 v = make_int4(0, 0, 0, 0);
    if (i0 + 3 < n) v = *(const int4*)(deg + i0);
    else {
        if (i0 + 0 < n) v.x = deg[i0 + 0];
        if (i0 + 1 < n) v.y = deg[i0 + 1];
        if (i0 + 2 < n) v.z = deg[i0 + 2];
        if (i0 + 3 < n) v.w = deg[i0 + 3];
    }
    __shared__ int sm[256];
    sm[t] = v.x + v.y + v.z + v.w;
    __syncthreads();
    for (int off = 1; off < 256; off <<= 1) {
        int x = (t >= off) ? sm[t - off] : 0;
        __syncthreads();
        sm[t] += x;
        __syncthreads();
    }
    int excl = (t > 0) ? sm[t - 1] : 0;
    if (i0 + 0 < n) rp[i0 + 0] = excl;
    if (i0 + 1 < n) rp[i0 + 1] = excl + v.x;
    if (i0 + 2 < n) rp[i0 + 2] = excl + v.x + v.y;
    if (i0 + 3 < n) rp[i0 + 3] = excl + v.x + v.y + v.z;
    if (t == 255) bs[b] = sm[255];
}

__global__ __launch_bounds__(256) void scan_offsets_kernel(
    int* __restrict__ rp_hf, const int* __restrict__ bs_hf,
    int* __restrict__ rp_tt, const int* __restrict__ bs_tt,
    int n, int nb, int E1, int E2)
{
    int gid = blockIdx.x;
    int* rp; const int* bs; int b; int E;
    if (gid < nb) { rp = rp_hf; bs = bs_hf; b = gid; E = E1; }
    else         { rp = rp_tt; bs = bs_tt; b = gid - nb; E = E2; }
    int t = threadIdx.x;
    int lane = t & 63;
    int partial = 0;
    for (int i = lane; i < b; i += 64) partial += bs[i];
    #pragma unroll
    for (int off = 32; off; off >>= 1) partial += __shfl_xor(partial, off);
    if (b == 0 && t == 0) rp[n] = E;
    if (partial == 0) return;
    int i0 = b * SCAN_EPB + t * 4;
    if (i0 + 0 < n) rp[i0 + 0] += partial;
    if (i0 + 1 < n) rp[i0 + 1] += partial;
    if (i0 + 2 < n) rp[i0 + 2] += partial;
    if (i0 + 3 < n) rp[i0 + 3] += partial;
}

__global__ void fill_both_kernel(
    const int* __restrict__ hf_src, const int* __restrict__ hf_dst,
    const unsigned short* __restrict__ rank_hf,
    const int* __restrict__ rp_hf, int* __restrict__ col_hf,
    const int* __restrict__ tt_src, const int* __restrict__ tt_dst,
    const unsigned short* __restrict__ rank_tt,
    const int* __restrict__ rp_tt, int* __restrict__ col_tt,
    int E1, int E2) {
    int i = blockIdx.x * blockDim.x + threadIdx.x;
    if (i < E1) {
        int d = hf_dst[i];
        col_hf[rp_hf[d] + rank_hf[i]] = hf_src[i];
    }
    if (i < E2) {
        int d = tt_dst[i];
        col_tt[rp_tt[d] + rank_tt[i]] = tt_src[i];
    }
}

// ---------------- segment mean (one wave per destination row) ----------------

__global__ __launch_bounds__(256) void agg_mean_kernel(
    const float* __restrict__ hsrc, const int* __restrict__ rowptr,
    const int* __restrict__ col, float* __restrict__ out, int ndst) {
    int w = (blockIdx.x * blockDim.x + threadIdx.x) >> 6;   // wave id = dst row
    int lane = threadIdx.x & 63;
    if (w >= ndst) return;
    int beg = rowptr[w];
    int end = rowptr[w + 1];
    int deg = end - beg;
    float ax[8], ay[8];
    #pragma unroll
    for (int u = 0; u < 8; ++u) { ax[u] = 0.f; ay[u] = 0.f; }
    const float* base = hsrc + lane * 2;
    for (int b = beg; b < end; b += 64) {
        int n = min(64, end - b);
        int myidx = (lane < n) ? col[b + lane] : 0;
        int j = 0;
        for (; j + 8 <= n; j += 8) {
            int s[8];
            #pragma unroll
            for (int u = 0; u < 8; ++u) s[u] = __shfl(myidx, j + u);
            float2 v[8];
            #pragma unroll
            for (int u = 0; u < 8; ++u) v[u] = *(const float2*)(base + (size_t)s[u] * D);
            #pragma unroll
            for (int u = 0; u < 8; ++u) { ax[u] += v[u].x; ay[u] += v[u].y; }
        }
        for (; j + 4 <= n; j += 4) {
            int s[4];
            #pragma unroll
            for (int u = 0; u < 4; ++u) s[u] = __shfl(myidx, j + u);
            float2 v[4];
            #pragma unroll
            for (int u = 0; u < 4; ++u) v[u] = *(const float2*)(base + (size_t)s[u] * D);
            #pragma unroll
            for (int u = 0; u < 4; ++u) { ax[u] += v[u].x; ay[u] += v[u].y; }
        }
        for (; j < n; ++j) {
            int s0 = __shfl(myidx, j);
            float2 v0 = *(const float2*)(base + (size_t)s0 * D);
            ax[0] += v0.x; ay[0] += v0.y;
        }
    }
    float inv = 1.0f / fmaxf((float)deg, 1.0f);
    float sx = ((ax[0] + ax[1]) + (ax[2] + ax[3])) + ((ax[4] + ax[5]) + (ax[6] + ax[7]));
    float sy = ((ay[0] + ay[1]) + (ay[2] + ay[3])) + ((ay[4] + ay[5]) + (ay[6] + ay[7]));
    float2 r; r.x = sx * inv; r.y = sy * inv;
    *(float2*)(out + (size_t)w * D + lane * 2) = r;
}

// ---------------- weight prep: transpose + bf16 hi/lo split + XOR swizzle ----------------
// wt layout: [pair(4)][s(2)][kk0(2)][plane(2)][n(128)*64 + (k ^ ((n&7)<<3))]  (shorts)
// pair -> (l,r): (0,0),(0,1),(1,1),(2,1); s=0 -> Wself (fc_self), s=1 -> Wneigh.

__global__ __launch_bounds__(256) void prep_weights_kernel(
    const float* __restrict__ Wself, const float* __restrict__ Wneigh,
    short* __restrict__ wt)
{
    int g = blockIdx.x * 256 + threadIdx.x;      // [0, 16384)
    int m = g >> 11;                             // matrix 0..7
    int e = g & 2047;
    int n  = e >> 4;                             // 0..127
    int kg = e & 15;
    int kk0 = kg >> 3;
    int kl0 = (kg & 7) * 8;
    int pair = m >> 1, s = m & 1;
    int l = (pair == 3) ? 2 : ((pair == 2) ? 1 : 0);
    int r = (pair == 0) ? 0 : 1;
    const float* W = (s ? Wneigh : Wself) + (size_t)(l * 2 + r) * D * D;
    s16x8 hv, lv;
    #pragma unroll
    for (int c = 0; c < 8; ++c) {
        int k = kk0 * 64 + kl0 + c;
        float x = W[(size_t)k * D + n];
        unsigned short h = f2bf(x);
        hv[c] = (short)h;
        lv[c] = (short)f2bf(x - bf2f(h));
    }
    int ksb = kl0 ^ ((n & 7) << 3);
    size_t base = ((((size_t)pair * 2 + s) * 2 + kk0) * 2) * 8192;
    *(s16x8*)&wt[base + n * 64 + ksb]        = hv;
    *(s16x8*)&wt[base + 8192 + n * 64 + ksb] = lv;
}

// ---------------- fused SAGE layer via split-bf16 MFMA ----------------
// Y = relu(A@W1 + B@W2 + bias) [+= old Y if ACC].
// BM=128, BN=128, 4 waves; wave w owns rows [w*32, w*32+32), all 128 cols.
// Split-3: Ah@Bh + Ah@Bl + Al@Bh per k-chunk of 16 (mfma_f32_32x32x16_bf16).
// LDS tiles [128][64] bf16, XOR-swizzled (k ^= (row&7)<<3) to kill the
// 32-way stride-128B frag-read conflict (G4).

template<bool ACC>
__global__ __launch_bounds__(256) void sage_mfma_kernel(
    const float* __restrict__ A, const float* __restrict__ B,
    const short* __restrict__ wtp, const float* __restrict__ bias,
    float* __restrict__ Y, int M)
{
    __shared__ short Ah[128 * 64];
    __shared__ short Al[128 * 64];
    __shared__ short Bh[128 * 64];
    __shared__ short Bl[128 * 64];

    const int tid = threadIdx.x;
    const int l = tid & 63, w = tid >> 6;
    const int row0 = blockIdx.x * 128;

    f32x16 acc[4] = {};

    const int s_r16 = tid >> 4;          // A-stage base row
    const int s_kq  = tid & 15;          // A-stage float4 index within 64-k
    const int arow  = w * 32 + (l & 31); // frag row (A) / within-tile
    const int fsw   = ((l & 31) & 7) << 3;  // frag read swizzle (same for A and B)
    const int afk   = (l >> 5) * 8;      // frag k sub-offset

    #pragma unroll 1
    for (int s = 0; s < 2; ++s) {
        const float* Ain = s ? B : A;
        #pragma unroll 1
        for (int kk0 = 0; kk0 < 2; ++kk0) {
            __syncthreads();
            // ---- stage A: fp32 -> bf16 hi/lo, swizzled ----
            #pragma unroll
            for (int j = 0; j < 8; ++j) {
                int r = s_r16 + 16 * j;
                int grow = row0 + r;
                float4 av = make_float4(0.f, 0.f, 0.f, 0.f);
                if (grow < M)
                    av = *(const float4*)(Ain + (size_t)grow * D + kk0 * 64 + s_kq * 4);
                s16x4 hv, lv;
                {
                    unsigned short h0 = f2bf(av.x); hv[0] = (short)h0; lv[0] = (short)f2bf(av.x - bf2f(h0));
                    unsigned short h1 = f2bf(av.y); hv[1] = (short)h1; lv[1] = (short)f2bf(av.y - bf2f(h1));
                    unsigned short h2 = f2bf(av.z); hv[2] = (short)h2; lv[2] = (short)f2bf(av.z - bf2f(h2));
                    unsigned short h3 = f2bf(av.w); hv[3] = (short)h3; lv[3] = (short)f2bf(av.w - bf2f(h3));
                }
                int ksb = (s_kq * 4) ^ ((r & 7) << 3);
                *(s16x4*)&Ah[r * 64 + ksb] = hv;
                *(s16x4*)&Al[r * 64 + ksb] = lv;
            }
            // ---- stage B: linear copy of pre-swizzled weight tile ----
            const short* wsrc = wtp + ((size_t)(s * 2 + kk0) * 2) * 8192;
            #pragma unroll
            for (int c = 0; c < 4; ++c) {
                *(s16x8*)&Bh[tid * 32 + c * 8] = *(const s16x8*)(wsrc + tid * 32 + c * 8);
                *(s16x8*)&Bl[tid * 32 + c * 8] = *(const s16x8*)(wsrc + 8192 + tid * 32 + c * 8);
            }
            __syncthreads();
            // ---- 4 k-chunks of 16 ----
            #pragma unroll
            for (int kc = 0; kc < 4; ++kc) {
                int ak = (kc * 16 + afk) ^ fsw;
                s16x8 ah = *(const s16x8*)&Ah[arow * 64 + ak];
                s16x8 al = *(const s16x8*)&Al[arow * 64 + ak];
                #pragma unroll
                for (int nt = 0; nt < 4; ++nt) {
                    int brow = nt * 32 + (l & 31);
                    s16x8 bh = *(const s16x8*)&Bh[brow * 64 + ak];
                    s16x8 bl = *(const s16x8*)&Bl[brow * 64 + ak];
                    acc[nt] = __builtin_amdgcn_mfma_f32_32x32x16_bf16(ah, bh, acc[nt], 0, 0, 0);
                    acc[nt] = __builtin_amdgcn_mfma_f32_32x32x16_bf16(ah, bl, acc[nt], 0, 0, 0);
                    acc[nt] = __builtin_amdgcn_mfma_f32_32x32x16_bf16(al, bh, acc[nt], 0, 0, 0);
                }
            }
        }
    }

    // ---- epilogue: D layout col=lane&31, row=(reg&3)+8*(reg>>2)+4*(lane>>5) ----
    const int colb = l & 31;
    const int rq4  = (l >> 5) * 4;
    float bias_c[4];
    #pragma unroll
    for (int nt = 0; nt < 4; ++nt) bias_c[nt] = bias[nt * 32 + colb];
    #pragma unroll
    for (int nt = 0; nt < 4; ++nt) {
        int col = nt * 32 + colb;
        #pragma unroll
        for (int g = 0; g < 4; ++g) {
            #pragma unroll
            for (int q = 0; q < 4; ++q) {
                int row = row0 + w * 32 + q + g * 8 + rq4;
                if (row < M) {
                    float v = fmaxf(acc[nt][g * 4 + q] + bias_c[nt], 0.f);
                    if (ACC) v += Y[(size_t)row * D + col];
                    Y[(size_t)row * D + col] = v;
                }
            }
        }
    }
}

// ---------------- launch ----------------

extern "C" void kernel_launch(void* const* d_in, const int* in_sizes, int n_in,
                              void* d_out, int out_size, void* d_ws, size_t ws_size,
                              hipStream_t stream) {
    const float* h_station = (const float*)d_in[0];
    const float* h_feature = (const float*)d_in[1];
    const float* Wself     = (const float*)d_in[2];
    const float* Wneigh    = (const float*)d_in[3];
    const float* bias      = (const float*)d_in[4];
    const int* hf_src = (const int*)d_in[5];
    const int* hf_dst = (const int*)d_in[6];
    const int* tt_src = (const int*)d_in[7];
    const int* tt_dst = (const int*)d_in[8];

    const int NS = in_sizes[0] / D;
    const int E1 = in_sizes[5];
    const int E2 = in_sizes[7];

    // workspace carve-up
    char* ws = (char*)d_ws;
    size_t off = 0;
    auto alloc = [&](size_t bytes) -> void* {
        void* p = ws + off;
        off = (off + bytes + 255) & ~(size_t)255;
        return p;
    };
    float* n_buf  = (float*)alloc((size_t)NS * D * sizeof(float));
    float* h_buf  = (float*)alloc((size_t)NS * D * sizeof(float));
    int* rp_hf    = (int*)alloc((size_t)(NS + 1) * sizeof(int));
    int* col_hf   = (int*)alloc((size_t)E1 * sizeof(int));
    int* rp_tt    = (int*)alloc((size_t)(NS + 1) * sizeof(int));
    int* col_tt   = (int*)alloc((size_t)E2 * sizeof(int));
    int* deg_hf   = (int*)alloc((size_t)NS * sizeof(int));
    int* deg_tt   = (int*)alloc((size_t)NS * sizeof(int));
    unsigned short* rank_hf = (unsigned short*)alloc((size_t)E1 * sizeof(unsigned short));
    unsigned short* rank_tt = (unsigned short*)alloc((size_t)E2 * sizeof(unsigned short));
    int  nb       = (NS + SCAN_EPB - 1) / SCAN_EPB;
    int* bs_hf    = (int*)alloc((size_t)nb * sizeof(int));
    int* bs_tt    = (int*)alloc((size_t)nb * sizeof(int));
    short* wt     = (short*)alloc((size_t)4 * 65536 * sizeof(short));   // 4 pairs x 64K shorts

    const int tpb = 256;
    int gz = (NS + tpb - 1) / tpb;
    int ge = (max(E1, E2) + tpb - 1) / tpb;

    prep_weights_kernel<<<64, tpb, 0, stream>>>(Wself, Wneigh, wt);
    zero2_kernel<<<gz, tpb, 0, stream>>>(deg_hf, deg_tt, NS);
    count_rank_kernel<<<ge, tpb, 0, stream>>>(hf_dst, tt_dst, deg_hf, deg_tt,
                                              rank_hf, rank_tt, E1, E2);
    scan_blocks_kernel<<<2 * nb, tpb, 0, stream>>>(deg_hf, rp_hf, bs_hf,
                                                   deg_tt, rp_tt, bs_tt, NS, nb);
    scan_offsets_kernel<<<2 * nb, tpb, 0, stream>>>(rp_hf, bs_hf, rp_tt, bs_tt,
                                                    NS, nb, E1, E2);
    fill_both_kernel<<<ge, tpb, 0, stream>>>(hf_src, hf_dst, rank_hf, rp_hf, col_hf,
                                             tt_src, tt_dst, rank_tt, rp_tt, col_tt, E1, E2);

    int gagg  = (NS * 64 + tpb - 1) / tpb;   // one wave per dst row
    int ggemm = (NS + 127) / 128;

    auto BI = [&](int lidx, int r) { return bias + (size_t)(lidx * 2 + r) * D; };
    auto WT = [&](int pair) { return wt + (size_t)pair * 65536; };

    float* out = (float*)d_out;

    // ---- layer 1 ----
    agg_mean_kernel<<<gagg, tpb, 0, stream>>>(h_feature, rp_hf, col_hf, n_buf, NS);
    sage_mfma_kernel<false><<<ggemm, tpb, 0, stream>>>(h_station, n_buf, WT(0), BI(0,0), h_buf, NS);
    agg_mean_kernel<<<gagg, tpb, 0, stream>>>(h_station, rp_tt, col_tt, n_buf, NS);
    sage_mfma_kernel<true><<<ggemm, tpb, 0, stream>>>(h_station, n_buf, WT(1), BI(0,1), h_buf, NS);

    // ---- layer 2 (in-place: each block reads/writes only its own rows) ----
    agg_mean_kernel<<<gagg, tpb, 0, stream>>>(h_buf, rp_tt, col_tt, n_buf, NS);
    sage_mfma_kernel<false><<<ggemm, tpb, 0, stream>>>(h_buf, n_buf, WT(2), BI(1,1), h_buf, NS);

    // ---- layer 3 ----
    agg_mean_kernel<<<gagg, tpb, 0, stream>>>(h_buf, rp_tt, col_tt, n_buf, NS);
    sage_mfma_kernel<false><<<ggemm, tpb, 0, stream>>>(h_buf, n_buf, WT(3), BI(2,1), out, NS);
}

// Round 7
// 363.649 us; speedup vs baseline: 65.2183x; 1.0464x over previous
//
#include <hip/hip_runtime.h>

#define D 128

typedef __attribute__((ext_vector_type(8)))  short s16x8;
typedef __attribute__((ext_vector_type(4)))  short s16x4;
typedef __attribute__((ext_vector_type(16))) float f32x16;

static __device__ __forceinline__ unsigned short f2bf(float x) {
    unsigned u = __builtin_bit_cast(unsigned, x);
    unsigned r = (u + 0x7FFF + ((u >> 16) & 1)) >> 16;   // RNE
    return (unsigned short)r;
}
static __device__ __forceinline__ float bf2f(unsigned short h) {
    unsigned u = ((unsigned)h) << 16;
    return __builtin_bit_cast(float, u);
}

// ---------------- CSR build (both graphs fused) ----------------

__global__ void zero2_kernel(int* __restrict__ a, int* __restrict__ b, int n) {
    int i = blockIdx.x * blockDim.x + threadIdx.x;
    if (i < n) { a[i] = 0; b[i] = 0; }
}

// Round-6: count_rank was 53us, latency-bound (VALUBusy 0.34%, 1 outstanding
// atomic/thread). ILP x4: int4 edge loads, 4 independent atomics in flight,
// ushort4 rank store.
__global__ void count_rank_kernel(const int* __restrict__ hf_dst, const int* __restrict__ tt_dst,
                                  int* __restrict__ deg_hf, int* __restrict__ deg_tt,
                                  unsigned short* __restrict__ rank_hf,
                                  unsigned short* __restrict__ rank_tt,
                                  int E1, int E2) {
    int i0 = (blockIdx.x * blockDim.x + threadIdx.x) * 4;
    if (i0 + 3 < E1) {
        int4 d = *(const int4*)(hf_dst + i0);
        int r0 = atomicAdd(&deg_hf[d.x], 1);
        int r1 = atomicAdd(&deg_hf[d.y], 1);
        int r2 = atomicAdd(&deg_hf[d.z], 1);
        int r3 = atomicAdd(&deg_hf[d.w], 1);
        *(ushort4*)(rank_hf + i0) = make_ushort4((unsigned short)r0, (unsigned short)r1,
                                                 (unsigned short)r2, (unsigned short)r3);
    } else {
        for (int j = 0; j < 4 && i0 + j < E1; ++j) {
            int r = atomicAdd(&deg_hf[hf_dst[i0 + j]], 1);
            rank_hf[i0 + j] = (unsigned short)r;
        }
    }
    if (i0 + 3 < E2) {
        int4 d = *(const int4*)(tt_dst + i0);
        int r0 = atomicAdd(&deg_tt[d.x], 1);
        int r1 = atomicAdd(&deg_tt[d.y], 1);
        int r2 = atomicAdd(&deg_tt[d.z], 1);
        int r3 = atomicAdd(&deg_tt[d.w], 1);
        *(ushort4*)(rank_tt + i0) = make_ushort4((unsigned short)r0, (unsigned short)r1,
                                                 (unsigned short)r2, (unsigned short)r3);
    } else {
        for (int j = 0; j < 4 && i0 + j < E2; ++j) {
            int r = atomicAdd(&deg_tt[tt_dst[i0 + j]], 1);
            rank_tt[i0 + j] = (unsigned short)r;
        }
    }
}

#define SCAN_EPB 1024

__global__ __launch_bounds__(256) void scan_blocks_kernel(
    const int* __restrict__ deg_hf, int* __restrict__ rp_hf, int* __restrict__ bs_hf,
    const int* __restrict__ deg_tt, int* __restrict__ rp_tt, int* __restrict__ bs_tt,
    int n, int nb)
{
    int gid = blockIdx.x;
    const int* deg; int* rp; int* bs; int b;
    if (gid < nb) { deg = deg_hf; rp = rp_hf; bs = bs_hf; b = gid; }
    else         { deg = deg_tt; rp = rp_tt; bs = bs_tt; b = gid - nb; }
    int t = threadIdx.x;
    int i0 = b * SCAN_EPB + t * 4;
    int4 v = make_int4(0, 0, 0, 0);
    if (i0 + 3 < n) v = *(const int4*)(deg + i0);
    else {
        if (i0 + 0 < n) v.x = deg[i0 + 0];
        if (i0 + 1 < n) v.y = deg[i0 + 1];
        if (i0 + 2 < n) v.z = deg[i0 + 2];
        if (i0 + 3 < n) v.w = deg[i0 + 3];
    }
    __shared__ int sm[256];
    sm[t] = v.x + v.y + v.z + v.w;
    __syncthreads();
    for (int off = 1; off < 256; off <<= 1) {
        int x = (t >= off) ? sm[t - off] : 0;
        __syncthreads();
        sm[t] += x;
        __syncthreads();
    }
    int excl = (t > 0) ? sm[t - 1] : 0;
    if (i0 + 0 < n) rp[i0 + 0] = excl;
    if (i0 + 1 < n) rp[i0 + 1] = excl + v.x;
    if (i0 + 2 < n) rp[i0 + 2] = excl + v.x + v.y;
    if (i0 + 3 < n) rp[i0 + 3] = excl + v.x + v.y + v.z;
    if (t == 255) bs[b] = sm[255];
}

__global__ __launch_bounds__(256) void scan_offsets_kernel(
    int* __restrict__ rp_hf, const int* __restrict__ bs_hf,
    int* __restrict__ rp_tt, const int* __restrict__ bs_tt,
    int n, int nb, int E1, int E2)
{
    int gid = blockIdx.x;
    int* rp; const int* bs; int b; int E;
    if (gid < nb) { rp = rp_hf; bs = bs_hf; b = gid; E = E1; }
    else         { rp = rp_tt; bs = bs_tt; b = gid - nb; E = E2; }
    int t = threadIdx.x;
    int lane = t & 63;
    int partial = 0;
    for (int i = lane; i < b; i += 64) partial += bs[i];
    #pragma unroll
    for (int off = 32; off; off >>= 1) partial += __shfl_xor(partial, off);
    if (b == 0 && t == 0) rp[n] = E;
    if (partial == 0) return;
    int i0 = b * SCAN_EPB + t * 4;
    if (i0 + 0 < n) rp[i0 + 0] += partial;
    if (i0 + 1 < n) rp[i0 + 1] += partial;
    if (i0 + 2 < n) rp[i0 + 2] += partial;
    if (i0 + 3 < n) rp[i0 + 3] += partial;
}

// atomic-free fill, ILP x4: col[rp[dst] + rank] = src
__global__ void fill_both_kernel(
    const int* __restrict__ hf_src, const int* __restrict__ hf_dst,
    const unsigned short* __restrict__ rank_hf,
    const int* __restrict__ rp_hf, int* __restrict__ col_hf,
    const int* __restrict__ tt_src, const int* __restrict__ tt_dst,
    const unsigned short* __restrict__ rank_tt,
    const int* __restrict__ rp_tt, int* __restrict__ col_tt,
    int E1, int E2) {
    int i0 = (blockIdx.x * blockDim.x + threadIdx.x) * 4;
    if (i0 + 3 < E1) {
        int4 d = *(const int4*)(hf_dst + i0);
        int4 s = *(const int4*)(hf_src + i0);
        ushort4 r = *(const ushort4*)(rank_hf + i0);
        int p0 = rp_hf[d.x], p1 = rp_hf[d.y], p2 = rp_hf[d.z], p3 = rp_hf[d.w];
        col_hf[p0 + r.x] = s.x;
        col_hf[p1 + r.y] = s.y;
        col_hf[p2 + r.z] = s.z;
        col_hf[p3 + r.w] = s.w;
    } else {
        for (int j = 0; j < 4 && i0 + j < E1; ++j)
            col_hf[rp_hf[hf_dst[i0 + j]] + rank_hf[i0 + j]] = hf_src[i0 + j];
    }
    if (i0 + 3 < E2) {
        int4 d = *(const int4*)(tt_dst + i0);
        int4 s = *(const int4*)(tt_src + i0);
        ushort4 r = *(const ushort4*)(rank_tt + i0);
        int p0 = rp_tt[d.x], p1 = rp_tt[d.y], p2 = rp_tt[d.z], p3 = rp_tt[d.w];
        col_tt[p0 + r.x] = s.x;
        col_tt[p1 + r.y] = s.y;
        col_tt[p2 + r.z] = s.z;
        col_tt[p3 + r.w] = s.w;
    } else {
        for (int j = 0; j < 4 && i0 + j < E2; ++j)
            col_tt[rp_tt[tt_dst[i0 + j]] + rank_tt[i0 + j]] = tt_src[i0 + j];
    }
}

// ---------------- segment mean (one wave per destination row) ----------------
// BF=false: gather fp32 rows (512B). BF=true: gather bf16 rows (256B) — halves
// gather traffic for layer 2/3 aggs whose source we control (GEMM dual-write).

template<bool BF>
__global__ __launch_bounds__(256) void agg_mean_kernel(
    const void* __restrict__ hsrc, const int* __restrict__ rowptr,
    const int* __restrict__ col, float* __restrict__ out, int ndst) {
    int w = (blockIdx.x * blockDim.x + threadIdx.x) >> 6;   // wave id = dst row
    int lane = threadIdx.x & 63;
    if (w >= ndst) return;
    int beg = rowptr[w];
    int end = rowptr[w + 1];
    int deg = end - beg;
    float ax[8], ay[8];
    #pragma unroll
    for (int u = 0; u < 8; ++u) { ax[u] = 0.f; ay[u] = 0.f; }
    const float* basef = (const float*)hsrc + lane * 2;
    const unsigned short* baseb = (const unsigned short*)hsrc + lane * 2;

    for (int b = beg; b < end; b += 64) {
        int n = min(64, end - b);
        int myidx = (lane < n) ? col[b + lane] : 0;
        int j = 0;
        for (; j + 8 <= n; j += 8) {
            int s[8];
            #pragma unroll
            for (int u = 0; u < 8; ++u) s[u] = __shfl(myidx, j + u);
            #pragma unroll
            for (int u = 0; u < 8; ++u) {
                if (BF) {
                    unsigned v = *(const unsigned*)(baseb + (size_t)s[u] * D);
                    ax[u] += __builtin_bit_cast(float, v << 16);
                    ay[u] += __builtin_bit_cast(float, v & 0xFFFF0000u);
                } else {
                    float2 v = *(const float2*)(basef + (size_t)s[u] * D);
                    ax[u] += v.x; ay[u] += v.y;
                }
            }
        }
        for (; j < n; ++j) {
            int s0 = __shfl(myidx, j);
            if (BF) {
                unsigned v = *(const unsigned*)(baseb + (size_t)s0 * D);
                ax[0] += __builtin_bit_cast(float, v << 16);
                ay[0] += __builtin_bit_cast(float, v & 0xFFFF0000u);
            } else {
                float2 v = *(const float2*)(basef + (size_t)s0 * D);
                ax[0] += v.x; ay[0] += v.y;
            }
        }
    }
    float inv = 1.0f / fmaxf((float)deg, 1.0f);
    float sx = ((ax[0] + ax[1]) + (ax[2] + ax[3])) + ((ax[4] + ax[5]) + (ax[6] + ax[7]));
    float sy = ((ay[0] + ay[1]) + (ay[2] + ay[3])) + ((ay[4] + ay[5]) + (ay[6] + ay[7]));
    float2 r; r.x = sx * inv; r.y = sy * inv;
    *(float2*)(out + (size_t)w * D + lane * 2) = r;
}

// ---------------- weight prep: transpose + bf16 hi/lo split + XOR swizzle ----------------

__global__ __launch_bounds__(256) void prep_weights_kernel(
    const float* __restrict__ Wself, const float* __restrict__ Wneigh,
    short* __restrict__ wt)
{
    int g = blockIdx.x * 256 + threadIdx.x;      // [0, 16384)
    int m = g >> 11;                             // matrix 0..7
    int e = g & 2047;
    int n  = e >> 4;                             // 0..127
    int kg = e & 15;
    int kk0 = kg >> 3;
    int kl0 = (kg & 7) * 8;
    int pair = m >> 1, s = m & 1;
    int l = (pair == 3) ? 2 : ((pair == 2) ? 1 : 0);
    int r = (pair == 0) ? 0 : 1;
    const float* W = (s ? Wneigh : Wself) + (size_t)(l * 2 + r) * D * D;
    s16x8 hv, lv;
    #pragma unroll
    for (int c = 0; c < 8; ++c) {
        int k = kk0 * 64 + kl0 + c;
        float x = W[(size_t)k * D + n];
        unsigned short h = f2bf(x);
        hv[c] = (short)h;
        lv[c] = (short)f2bf(x - bf2f(h));
    }
    int ksb = kl0 ^ ((n & 7) << 3);
    size_t base = ((((size_t)pair * 2 + s) * 2 + kk0) * 2) * 8192;
    *(s16x8*)&wt[base + n * 64 + ksb]        = hv;
    *(s16x8*)&wt[base + 8192 + n * 64 + ksb] = lv;
}

// ---------------- fused SAGE layer via split-bf16 MFMA ----------------
// Y = relu(A@W1 + B@W2 + bias) [+= old Y if ACC]; optional bf16 dual-write of Y.

template<bool ACC>
__global__ __launch_bounds__(256) void sage_mfma_kernel(
    const float* __restrict__ A, const float* __restrict__ B,
    const short* __restrict__ wtp, const float* __restrict__ bias,
    float* __restrict__ Y, unsigned short* __restrict__ Ybf, int M)
{
    __shared__ short Ah[128 * 64];
    __shared__ short Al[128 * 64];
    __shared__ short Bh[128 * 64];
    __shared__ short Bl[128 * 64];

    const int tid = threadIdx.x;
    const int l = tid & 63, w = tid >> 6;
    const int row0 = blockIdx.x * 128;

    f32x16 acc[4] = {};

    const int s_r16 = tid >> 4;
    const int s_kq  = tid & 15;
    const int arow  = w * 32 + (l & 31);
    const int fsw   = ((l & 31) & 7) << 3;
    const int afk   = (l >> 5) * 8;

    #pragma unroll 1
    for (int s = 0; s < 2; ++s) {
        const float* Ain = s ? B : A;
        #pragma unroll 1
        for (int kk0 = 0; kk0 < 2; ++kk0) {
            __syncthreads();
            #pragma unroll
            for (int j = 0; j < 8; ++j) {
                int r = s_r16 + 16 * j;
                int grow = row0 + r;
                float4 av = make_float4(0.f, 0.f, 0.f, 0.f);
                if (grow < M)
                    av = *(const float4*)(Ain + (size_t)grow * D + kk0 * 64 + s_kq * 4);
                s16x4 hv, lv;
                {
                    unsigned short h0 = f2bf(av.x); hv[0] = (short)h0; lv[0] = (short)f2bf(av.x - bf2f(h0));
                    unsigned short h1 = f2bf(av.y); hv[1] = (short)h1; lv[1] = (short)f2bf(av.y - bf2f(h1));
                    unsigned short h2 = f2bf(av.z); hv[2] = (short)h2; lv[2] = (short)f2bf(av.z - bf2f(h2));
                    unsigned short h3 = f2bf(av.w); hv[3] = (short)h3; lv[3] = (short)f2bf(av.w - bf2f(h3));
                }
                int ksb = (s_kq * 4) ^ ((r & 7) << 3);
                *(s16x4*)&Ah[r * 64 + ksb] = hv;
                *(s16x4*)&Al[r * 64 + ksb] = lv;
            }
            const short* wsrc = wtp + ((size_t)(s * 2 + kk0) * 2) * 8192;
            #pragma unroll
            for (int c = 0; c < 4; ++c) {
                *(s16x8*)&Bh[tid * 32 + c * 8] = *(const s16x8*)(wsrc + tid * 32 + c * 8);
                *(s16x8*)&Bl[tid * 32 + c * 8] = *(const s16x8*)(wsrc + 8192 + tid * 32 + c * 8);
            }
            __syncthreads();
            #pragma unroll
            for (int kc = 0; kc < 4; ++kc) {
                int ak = (kc * 16 + afk) ^ fsw;
                s16x8 ah = *(const s16x8*)&Ah[arow * 64 + ak];
                s16x8 al = *(const s16x8*)&Al[arow * 64 + ak];
                #pragma unroll
                for (int nt = 0; nt < 4; ++nt) {
                    int brow = nt * 32 + (l & 31);
                    s16x8 bh = *(const s16x8*)&Bh[brow * 64 + ak];
                    s16x8 bl = *(const s16x8*)&Bl[brow * 64 + ak];
                    acc[nt] = __builtin_amdgcn_mfma_f32_32x32x16_bf16(ah, bh, acc[nt], 0, 0, 0);
                    acc[nt] = __builtin_amdgcn_mfma_f32_32x32x16_bf16(ah, bl, acc[nt], 0, 0, 0);
                    acc[nt] = __builtin_amdgcn_mfma_f32_32x32x16_bf16(al, bh, acc[nt], 0, 0, 0);
                }
            }
        }
    }

    // D layout: col=lane&31, row=(reg&3)+8*(reg>>2)+4*(lane>>5)
    const int colb = l & 31;
    const int rq4  = (l >> 5) * 4;
    float bias_c[4];
    #pragma unroll
    for (int nt = 0; nt < 4; ++nt) bias_c[nt] = bias[nt * 32 + colb];
    #pragma unroll
    for (int nt = 0; nt < 4; ++nt) {
        int col = nt * 32 + colb;
        #pragma unroll
        for (int g = 0; g < 4; ++g) {
            #pragma unroll
            for (int q = 0; q < 4; ++q) {
                int row = row0 + w * 32 + q + g * 8 + rq4;
                if (row < M) {
                    float v = fmaxf(acc[nt][g * 4 + q] + bias_c[nt], 0.f);
                    if (ACC) v += Y[(size_t)row * D + col];
                    Y[(size_t)row * D + col] = v;
                    if (Ybf) Ybf[(size_t)row * D + col] = f2bf(v);
                }
            }
        }
    }
}

// ---------------- launch ----------------

extern "C" void kernel_launch(void* const* d_in, const int* in_sizes, int n_in,
                              void* d_out, int out_size, void* d_ws, size_t ws_size,
                              hipStream_t stream) {
    const float* h_station = (const float*)d_in[0];
    const float* h_feature = (const float*)d_in[1];
    const float* Wself     = (const float*)d_in[2];
    const float* Wneigh    = (const float*)d_in[3];
    const float* bias      = (const float*)d_in[4];
    const int* hf_src = (const int*)d_in[5];
    const int* hf_dst = (const int*)d_in[6];
    const int* tt_src = (const int*)d_in[7];
    const int* tt_dst = (const int*)d_in[8];

    const int NS = in_sizes[0] / D;
    const int E1 = in_sizes[5];
    const int E2 = in_sizes[7];

    // workspace carve-up
    char* ws = (char*)d_ws;
    size_t off = 0;
    auto alloc = [&](size_t bytes) -> void* {
        void* p = ws + off;
        off = (off + bytes + 255) & ~(size_t)255;
        return p;
    };
    float* n_buf  = (float*)alloc((size_t)NS * D * sizeof(float));
    float* h_buf  = (float*)alloc((size_t)NS * D * sizeof(float));
    unsigned short* hbuf_bf = (unsigned short*)alloc((size_t)NS * D * sizeof(unsigned short));
    int* rp_hf    = (int*)alloc((size_t)(NS + 1) * sizeof(int));
    int* col_hf   = (int*)alloc((size_t)E1 * sizeof(int));
    int* rp_tt    = (int*)alloc((size_t)(NS + 1) * sizeof(int));
    int* col_tt   = (int*)alloc((size_t)E2 * sizeof(int));
    int* deg_hf   = (int*)alloc((size_t)NS * sizeof(int));
    int* deg_tt   = (int*)alloc((size_t)NS * sizeof(int));
    unsigned short* rank_hf = (unsigned short*)alloc((size_t)E1 * sizeof(unsigned short));
    unsigned short* rank_tt = (unsigned short*)alloc((size_t)E2 * sizeof(unsigned short));
    int  nb       = (NS + SCAN_EPB - 1) / SCAN_EPB;
    int* bs_hf    = (int*)alloc((size_t)nb * sizeof(int));
    int* bs_tt    = (int*)alloc((size_t)nb * sizeof(int));
    short* wt     = (short*)alloc((size_t)4 * 65536 * sizeof(short));

    const int tpb = 256;
    int gz  = (NS + tpb - 1) / tpb;
    int ge4 = ((max(E1, E2) + 3) / 4 + tpb - 1) / tpb;   // ILP x4 edge kernels

    prep_weights_kernel<<<64, tpb, 0, stream>>>(Wself, Wneigh, wt);
    zero2_kernel<<<gz, tpb, 0, stream>>>(deg_hf, deg_tt, NS);
    count_rank_kernel<<<ge4, tpb, 0, stream>>>(hf_dst, tt_dst, deg_hf, deg_tt,
                                               rank_hf, rank_tt, E1, E2);
    scan_blocks_kernel<<<2 * nb, tpb, 0, stream>>>(deg_hf, rp_hf, bs_hf,
                                                   deg_tt, rp_tt, bs_tt, NS, nb);
    scan_offsets_kernel<<<2 * nb, tpb, 0, stream>>>(rp_hf, bs_hf, rp_tt, bs_tt,
                                                    NS, nb, E1, E2);
    fill_both_kernel<<<ge4, tpb, 0, stream>>>(hf_src, hf_dst, rank_hf, rp_hf, col_hf,
                                              tt_src, tt_dst, rank_tt, rp_tt, col_tt, E1, E2);

    int gagg  = (NS * 64 + tpb - 1) / tpb;   // one wave per dst row
    int ggemm = (NS + 127) / 128;

    auto BI = [&](int lidx, int r) { return bias + (size_t)(lidx * 2 + r) * D; };
    auto WT = [&](int pair) { return wt + (size_t)pair * 65536; };

    float* out = (float*)d_out;

    // ---- layer 1 ----
    agg_mean_kernel<false><<<gagg, tpb, 0, stream>>>(h_feature, rp_hf, col_hf, n_buf, NS);
    sage_mfma_kernel<false><<<ggemm, tpb, 0, stream>>>(h_station, n_buf, WT(0), BI(0,0), h_buf, hbuf_bf, NS);
    agg_mean_kernel<false><<<gagg, tpb, 0, stream>>>(h_station, rp_tt, col_tt, n_buf, NS);
    sage_mfma_kernel<true><<<ggemm, tpb, 0, stream>>>(h_station, n_buf, WT(1), BI(0,1), h_buf, hbuf_bf, NS);

    // ---- layer 2 (in-place: each block reads/writes only its own rows) ----
    agg_mean_kernel<true><<<gagg, tpb, 0, stream>>>(hbuf_bf, rp_tt, col_tt, n_buf, NS);
    sage_mfma_kernel<false><<<ggemm, tpb, 0, stream>>>(h_buf, n_buf, WT(2), BI(1,1), h_buf, hbuf_bf, NS);

    // ---- layer 3 ----
    agg_mean_kernel<true><<<gagg, tpb, 0, stream>>>(hbuf_bf, rp_tt, col_tt, n_buf, NS);
    sage_mfma_kernel<false><<<ggemm, tpb, 0, stream>>>(h_buf, n_buf, WT(3), BI(2,1), out, nullptr, NS);
}

// Round 8
// 339.985 us; speedup vs baseline: 69.7577x; 1.0696x over previous
//
#include <hip/hip_runtime.h>

#define D 128

typedef __attribute__((ext_vector_type(8)))  short s16x8;
typedef __attribute__((ext_vector_type(4)))  short s16x4;
typedef __attribute__((ext_vector_type(16))) float f32x16;

static __device__ __forceinline__ unsigned short f2bf(float x) {
    unsigned u = __builtin_bit_cast(unsigned, x);
    unsigned r = (u + 0x7FFF + ((u >> 16) & 1)) >> 16;   // RNE
    return (unsigned short)r;
}
static __device__ __forceinline__ float bf2f(unsigned short h) {
    unsigned u = ((unsigned)h) << 16;
    return __builtin_bit_cast(float, u);
}

// ---------------- CSR build ----------------

__global__ void zero2_kernel(int* __restrict__ a, int* __restrict__ b, int n) {
    int i = blockIdx.x * blockDim.x + threadIdx.x;
    if (i < n) { a[i] = 0; b[i] = 0; }
}

// Round-7 lesson: count_rank is an L2 atomic-throughput wall (~53us) — ILP x4
// did NOT help (occupancy 63->19%, time unchanged). Scalar form, accepted for now.
__global__ void count_rank_kernel(const int* __restrict__ hf_dst, const int* __restrict__ tt_dst,
                                  int* __restrict__ deg_hf, int* __restrict__ deg_tt,
                                  unsigned short* __restrict__ rank_hf,
                                  unsigned short* __restrict__ rank_tt,
                                  int E1, int E2) {
    int i = blockIdx.x * blockDim.x + threadIdx.x;
    if (i < E1) {
        int r = atomicAdd(&deg_hf[hf_dst[i]], 1);
        rank_hf[i] = (unsigned short)r;
    }
    if (i < E2) {
        int r = atomicAdd(&deg_tt[tt_dst[i]], 1);
        rank_tt[i] = (unsigned short)r;
    }
}

#define SCAN_EPB 1024

__global__ __launch_bounds__(256) void scan_blocks_kernel(
    const int* __restrict__ deg_hf, int* __restrict__ rp_hf, int* __restrict__ bs_hf,
    const int* __restrict__ deg_tt, int* __restrict__ rp_tt, int* __restrict__ bs_tt,
    int n, int nb)
{
    int gid = blockIdx.x;
    const int* deg; int* rp; int* bs; int b;
    if (gid < nb) { deg = deg_hf; rp = rp_hf; bs = bs_hf; b = gid; }
    else         { deg = deg_tt; rp = rp_tt; bs = bs_tt; b = gid - nb; }
    int t = threadIdx.x;
    int i0 = b * SCAN_EPB + t * 4;
    int4 v = make_int4(0, 0, 0, 0);
    if (i0 + 3 < n) v = *(const int4*)(deg + i0);
    else {
        if (i0 + 0 < n) v.x = deg[i0 + 0];
        if (i0 + 1 < n) v.y = deg[i0 + 1];
        if (i0 + 2 < n) v.z = deg[i0 + 2];
        if (i0 + 3 < n) v.w = deg[i0 + 3];
    }
    __shared__ int sm[256];
    sm[t] = v.x + v.y + v.z + v.w;
    __syncthreads();
    for (int off = 1; off < 256; off <<= 1) {
        int x = (t >= off) ? sm[t - off] : 0;
        __syncthreads();
        sm[t] += x;
        __syncthreads();
    }
    int excl = (t > 0) ? sm[t - 1] : 0;
    if (i0 + 0 < n) rp[i0 + 0] = excl;
    if (i0 + 1 < n) rp[i0 + 1] = excl + v.x;
    if (i0 + 2 < n) rp[i0 + 2] = excl + v.x + v.y;
    if (i0 + 3 < n) rp[i0 + 3] = excl + v.x + v.y + v.z;
    if (t == 255) bs[b] = sm[255];
}

__global__ __launch_bounds__(256) void scan_offsets_kernel(
    int* __restrict__ rp_hf, const int* __restrict__ bs_hf,
    int* __restrict__ rp_tt, const int* __restrict__ bs_tt,
    int n, int nb, int E1, int E2)
{
    int gid = blockIdx.x;
    int* rp; const int* bs; int b; int E;
    if (gid < nb) { rp = rp_hf; bs = bs_hf; b = gid; E = E1; }
    else         { rp = rp_tt; bs = bs_tt; b = gid - nb; E = E2; }
    int t = threadIdx.x;
    int lane = t & 63;
    int partial = 0;
    for (int i = lane; i < b; i += 64) partial += bs[i];
    #pragma unroll
    for (int off = 32; off; off >>= 1) partial += __shfl_xor(partial, off);
    if (b == 0 && t == 0) rp[n] = E;
    if (partial == 0) return;
    int i0 = b * SCAN_EPB + t * 4;
    if (i0 + 0 < n) rp[i0 + 0] += partial;
    if (i0 + 1 < n) rp[i0 + 1] += partial;
    if (i0 + 2 < n) rp[i0 + 2] += partial;
    if (i0 + 3 < n) rp[i0 + 3] += partial;
}

__global__ void fill_both_kernel(
    const int* __restrict__ hf_src, const int* __restrict__ hf_dst,
    const unsigned short* __restrict__ rank_hf,
    const int* __restrict__ rp_hf, int* __restrict__ col_hf,
    const int* __restrict__ tt_src, const int* __restrict__ tt_dst,
    const unsigned short* __restrict__ rank_tt,
    const int* __restrict__ rp_tt, int* __restrict__ col_tt,
    int E1, int E2) {
    int i0 = (blockIdx.x * blockDim.x + threadIdx.x) * 4;
    if (i0 + 3 < E1) {
        int4 d = *(const int4*)(hf_dst + i0);
        int4 s = *(const int4*)(hf_src + i0);
        ushort4 r = *(const ushort4*)(rank_hf + i0);
        int p0 = rp_hf[d.x], p1 = rp_hf[d.y], p2 = rp_hf[d.z], p3 = rp_hf[d.w];
        col_hf[p0 + r.x] = s.x;
        col_hf[p1 + r.y] = s.y;
        col_hf[p2 + r.z] = s.z;
        col_hf[p3 + r.w] = s.w;
    } else {
        for (int j = 0; j < 4 && i0 + j < E1; ++j)
            col_hf[rp_hf[hf_dst[i0 + j]] + rank_hf[i0 + j]] = hf_src[i0 + j];
    }
    if (i0 + 3 < E2) {
        int4 d = *(const int4*)(tt_dst + i0);
        int4 s = *(const int4*)(tt_src + i0);
        ushort4 r = *(const ushort4*)(rank_tt + i0);
        int p0 = rp_tt[d.x], p1 = rp_tt[d.y], p2 = rp_tt[d.z], p3 = rp_tt[d.w];
        col_tt[p0 + r.x] = s.x;
        col_tt[p1 + r.y] = s.y;
        col_tt[p2 + r.z] = s.z;
        col_tt[p3 + r.w] = s.w;
    } else {
        for (int j = 0; j < 4 && i0 + j < E2; ++j)
            col_tt[rp_tt[tt_dst[i0 + j]] + rank_tt[i0 + j]] = tt_src[i0 + j];
    }
}

// ---------------- fp32 -> bf16 hi/lo split (row-major passthrough) ----------------

__global__ void split_rows_kernel(const float* __restrict__ in,
                                  unsigned short* __restrict__ hi,
                                  unsigned short* __restrict__ lo, int nelem) {
    int i = (blockIdx.x * blockDim.x + threadIdx.x) * 4;
    if (i >= nelem) return;
    float4 v = *(const float4*)(in + i);
    s16x4 hv, lv;
    unsigned short h0 = f2bf(v.x); hv[0] = (short)h0; lv[0] = (short)f2bf(v.x - bf2f(h0));
    unsigned short h1 = f2bf(v.y); hv[1] = (short)h1; lv[1] = (short)f2bf(v.y - bf2f(h1));
    unsigned short h2 = f2bf(v.z); hv[2] = (short)h2; lv[2] = (short)f2bf(v.z - bf2f(h2));
    unsigned short h3 = f2bf(v.w); hv[3] = (short)h3; lv[3] = (short)f2bf(v.w - bf2f(h3));
    *(s16x4*)(hi + i) = hv;
    *(s16x4*)(lo + i) = lv;
}

// ---------------- segment mean (one wave per dst row), outputs bf16 hi/lo ----------------
// SRCBF=false: gather fp32 rows (512B); SRCBF=true: gather bf16-hi rows (256B).

template<bool SRCBF>
__global__ __launch_bounds__(256) void agg_mean_kernel(
    const void* __restrict__ hsrc, const int* __restrict__ rowptr,
    const int* __restrict__ col,
    unsigned short* __restrict__ oh, unsigned short* __restrict__ ol, int ndst) {
    int w = (blockIdx.x * blockDim.x + threadIdx.x) >> 6;
    int lane = threadIdx.x & 63;
    if (w >= ndst) return;
    int beg = rowptr[w];
    int end = rowptr[w + 1];
    int deg = end - beg;
    float ax[8], ay[8];
    #pragma unroll
    for (int u = 0; u < 8; ++u) { ax[u] = 0.f; ay[u] = 0.f; }
    const float* basef = (const float*)hsrc + lane * 2;
    const unsigned short* baseb = (const unsigned short*)hsrc + lane * 2;

    for (int b = beg; b < end; b += 64) {
        int n = min(64, end - b);
        int myidx = (lane < n) ? col[b + lane] : 0;
        int j = 0;
        for (; j + 8 <= n; j += 8) {
            int s[8];
            #pragma unroll
            for (int u = 0; u < 8; ++u) s[u] = __shfl(myidx, j + u);
            #pragma unroll
            for (int u = 0; u < 8; ++u) {
                if (SRCBF) {
                    unsigned v = *(const unsigned*)(baseb + (size_t)s[u] * D);
                    ax[u] += __builtin_bit_cast(float, v << 16);
                    ay[u] += __builtin_bit_cast(float, v & 0xFFFF0000u);
                } else {
                    float2 v = *(const float2*)(basef + (size_t)s[u] * D);
                    ax[u] += v.x; ay[u] += v.y;
                }
            }
        }
        for (; j < n; ++j) {
            int s0 = __shfl(myidx, j);
            if (SRCBF) {
                unsigned v = *(const unsigned*)(baseb + (size_t)s0 * D);
                ax[0] += __builtin_bit_cast(float, v << 16);
                ay[0] += __builtin_bit_cast(float, v & 0xFFFF0000u);
            } else {
                float2 v = *(const float2*)(basef + (size_t)s0 * D);
                ax[0] += v.x; ay[0] += v.y;
            }
        }
    }
    float inv = 1.0f / fmaxf((float)deg, 1.0f);
    float sx = (((ax[0] + ax[1]) + (ax[2] + ax[3])) + ((ax[4] + ax[5]) + (ax[6] + ax[7]))) * inv;
    float sy = (((ay[0] + ay[1]) + (ay[2] + ay[3])) + ((ay[4] + ay[5]) + (ay[6] + ay[7]))) * inv;
    unsigned short hx = f2bf(sx), hy = f2bf(sy);
    unsigned short lx = f2bf(sx - bf2f(hx)), ly = f2bf(sy - bf2f(hy));
    ((unsigned*)oh)[(size_t)w * 64 + lane] = (unsigned)hx | ((unsigned)hy << 16);
    ((unsigned*)ol)[(size_t)w * 64 + lane] = (unsigned)lx | ((unsigned)ly << 16);
}

// ---------------- weight prep: transpose + bf16 hi/lo split + XOR swizzle ----------------

__global__ __launch_bounds__(256) void prep_weights_kernel(
    const float* __restrict__ Wself, const float* __restrict__ Wneigh,
    short* __restrict__ wt)
{
    int g = blockIdx.x * 256 + threadIdx.x;      // [0, 16384)
    int m = g >> 11;
    int e = g & 2047;
    int n  = e >> 4;
    int kg = e & 15;
    int kk0 = kg >> 3;
    int kl0 = (kg & 7) * 8;
    int pair = m >> 1, s = m & 1;
    int l = (pair == 3) ? 2 : ((pair == 2) ? 1 : 0);
    int r = (pair == 0) ? 0 : 1;
    const float* W = (s ? Wneigh : Wself) + (size_t)(l * 2 + r) * D * D;
    s16x8 hv, lv;
    #pragma unroll
    for (int c = 0; c < 8; ++c) {
        int k = kk0 * 64 + kl0 + c;
        float x = W[(size_t)k * D + n];
        unsigned short h = f2bf(x);
        hv[c] = (short)h;
        lv[c] = (short)f2bf(x - bf2f(h));
    }
    int ksb = kl0 ^ ((n & 7) << 3);
    size_t base = ((((size_t)pair * 2 + s) * 2 + kk0) * 2) * 8192;
    *(s16x8*)&wt[base + n * 64 + ksb]        = hv;
    *(s16x8*)&wt[base + 8192 + n * 64 + ksb] = lv;
}

// ---------------- fused SAGE layer via split-bf16 MFMA (pre-split inputs) ----------------
// Y = relu(Aself@W1 + Aneigh@W2 + bias) [+ hi/lo readback if ACC].
// All activations arrive as bf16 hi/lo pairs -> staging is a pure copy
// (8x16B load + 8x ds_write_b128 per thread per stage), no conversion math.

template<bool ACC, bool WF32, bool WBF>
__global__ __launch_bounds__(256) void sage_mfma_kernel(
    const unsigned short* __restrict__ Ah_g, const unsigned short* __restrict__ Al_g,
    const unsigned short* __restrict__ Nh_g, const unsigned short* __restrict__ Nl_g,
    const short* __restrict__ wtp, const float* __restrict__ bias,
    float* __restrict__ Yf, unsigned short* __restrict__ Yh, unsigned short* __restrict__ Yl,
    int M)
{
    __shared__ short Ah[128 * 64];
    __shared__ short Al[128 * 64];
    __shared__ short Bh[128 * 64];
    __shared__ short Bl[128 * 64];

    const int tid = threadIdx.x;
    const int l = tid & 63, w = tid >> 6;
    const int row0 = blockIdx.x * 128;

    f32x16 acc[4] = {};

    const int s_row = tid >> 1;           // 0..127
    const int s_kq  = (tid & 1) * 32;     // 0 or 32
    const int s_sw  = (s_row & 7) << 3;
    const int arow  = w * 32 + (l & 31);
    const int fsw   = ((l & 31) & 7) << 3;
    const int afk   = (l >> 5) * 8;

    #pragma unroll 1
    for (int s = 0; s < 2; ++s) {
        const unsigned short* Hg = s ? Nh_g : Ah_g;
        const unsigned short* Lg = s ? Nl_g : Al_g;
        #pragma unroll 1
        for (int kk0 = 0; kk0 < 2; ++kk0) {
            __syncthreads();
            // activation staging: pure copy with XOR swizzle
            {
                int grow = row0 + s_row;
                const unsigned short* hrow = Hg + (size_t)grow * D + kk0 * 64;
                const unsigned short* lrow = Lg + (size_t)grow * D + kk0 * 64;
                #pragma unroll
                for (int c = 0; c < 4; ++c) {
                    int k = s_kq + c * 8;
                    s16x8 hv = {}, lv = {};
                    if (grow < M) {
                        hv = *(const s16x8*)(hrow + k);
                        lv = *(const s16x8*)(lrow + k);
                    }
                    *(s16x8*)&Ah[s_row * 64 + (k ^ s_sw)] = hv;
                    *(s16x8*)&Al[s_row * 64 + (k ^ s_sw)] = lv;
                }
            }
            // weight staging: linear copy of pre-swizzled tile
            const short* wsrc = wtp + ((size_t)(s * 2 + kk0) * 2) * 8192;
            #pragma unroll
            for (int c = 0; c < 4; ++c) {
                *(s16x8*)&Bh[tid * 32 + c * 8] = *(const s16x8*)(wsrc + tid * 32 + c * 8);
                *(s16x8*)&Bl[tid * 32 + c * 8] = *(const s16x8*)(wsrc + 8192 + tid * 32 + c * 8);
            }
            __syncthreads();
            #pragma unroll
            for (int kc = 0; kc < 4; ++kc) {
                int ak = (kc * 16 + afk) ^ fsw;
                s16x8 ah = *(const s16x8*)&Ah[arow * 64 + ak];
                s16x8 al = *(const s16x8*)&Al[arow * 64 + ak];
                #pragma unroll
                for (int nt = 0; nt < 4; ++nt) {
                    int brow = nt * 32 + (l & 31);
                    s16x8 bh = *(const s16x8*)&Bh[brow * 64 + ak];
                    s16x8 bl = *(const s16x8*)&Bl[brow * 64 + ak];
                    acc[nt] = __builtin_amdgcn_mfma_f32_32x32x16_bf16(ah, bh, acc[nt], 0, 0, 0);
                    acc[nt] = __builtin_amdgcn_mfma_f32_32x32x16_bf16(ah, bl, acc[nt], 0, 0, 0);
                    acc[nt] = __builtin_amdgcn_mfma_f32_32x32x16_bf16(al, bh, acc[nt], 0, 0, 0);
                }
            }
        }
    }

    // D layout: col=lane&31, row=(reg&3)+8*(reg>>2)+4*(lane>>5)
    const int colb = l & 31;
    const int rq4  = (l >> 5) * 4;
    float bias_c[4];
    #pragma unroll
    for (int nt = 0; nt < 4; ++nt) bias_c[nt] = bias[nt * 32 + colb];
    #pragma unroll
    for (int nt = 0; nt < 4; ++nt) {
        int col = nt * 32 + colb;
        #pragma unroll
        for (int g = 0; g < 4; ++g) {
            #pragma unroll
            for (int q = 0; q < 4; ++q) {
                int row = row0 + w * 32 + q + g * 8 + rq4;
                if (row < M) {
                    size_t idx = (size_t)row * D + col;
                    float v = fmaxf(acc[nt][g * 4 + q] + bias_c[nt], 0.f);
                    if (ACC) v += bf2f(Yh[idx]) + bf2f(Yl[idx]);
                    if (WF32) Yf[idx] = v;
                    if (WBF) {
                        unsigned short h = f2bf(v);
                        Yh[idx] = h;
                        Yl[idx] = f2bf(v - bf2f(h));
                    }
                }
            }
        }
    }
}

// ---------------- launch ----------------

extern "C" void kernel_launch(void* const* d_in, const int* in_sizes, int n_in,
                              void* d_out, int out_size, void* d_ws, size_t ws_size,
                              hipStream_t stream) {
    const float* h_station = (const float*)d_in[0];
    const float* h_feature = (const float*)d_in[1];
    const float* Wself     = (const float*)d_in[2];
    const float* Wneigh    = (const float*)d_in[3];
    const float* bias      = (const float*)d_in[4];
    const int* hf_src = (const int*)d_in[5];
    const int* hf_dst = (const int*)d_in[6];
    const int* tt_src = (const int*)d_in[7];
    const int* tt_dst = (const int*)d_in[8];

    const int NS = in_sizes[0] / D;
    const int E1 = in_sizes[5];
    const int E2 = in_sizes[7];

    // workspace carve-up
    char* ws = (char*)d_ws;
    size_t off = 0;
    auto alloc = [&](size_t bytes) -> void* {
        void* p = ws + off;
        off = (off + bytes + 255) & ~(size_t)255;
        return p;
    };
    unsigned short* st_h  = (unsigned short*)alloc((size_t)NS * D * 2);
    unsigned short* st_l  = (unsigned short*)alloc((size_t)NS * D * 2);
    unsigned short* n_h   = (unsigned short*)alloc((size_t)NS * D * 2);
    unsigned short* n_l   = (unsigned short*)alloc((size_t)NS * D * 2);
    unsigned short* hb_h  = (unsigned short*)alloc((size_t)NS * D * 2);
    unsigned short* hb_l  = (unsigned short*)alloc((size_t)NS * D * 2);
    int* rp_hf    = (int*)alloc((size_t)(NS + 1) * sizeof(int));
    int* col_hf   = (int*)alloc((size_t)E1 * sizeof(int));
    int* rp_tt    = (int*)alloc((size_t)(NS + 1) * sizeof(int));
    int* col_tt   = (int*)alloc((size_t)E2 * sizeof(int));
    int* deg_hf   = (int*)alloc((size_t)NS * sizeof(int));
    int* deg_tt   = (int*)alloc((size_t)NS * sizeof(int));
    unsigned short* rank_hf = (unsigned short*)alloc((size_t)E1 * 2);
    unsigned short* rank_tt = (unsigned short*)alloc((size_t)E2 * 2);
    int  nb       = (NS + SCAN_EPB - 1) / SCAN_EPB;
    int* bs_hf    = (int*)alloc((size_t)nb * sizeof(int));
    int* bs_tt    = (int*)alloc((size_t)nb * sizeof(int));
    short* wt     = (short*)alloc((size_t)4 * 65536 * sizeof(short));

    const int tpb = 256;
    int gz  = (NS + tpb - 1) / tpb;
    int ge  = (max(E1, E2) + tpb - 1) / tpb;
    int ge4 = ((max(E1, E2) + 3) / 4 + tpb - 1) / tpb;
    int gsp = ((NS * D / 4) + tpb - 1) / tpb;

    prep_weights_kernel<<<64, tpb, 0, stream>>>(Wself, Wneigh, wt);
    split_rows_kernel<<<gsp, tpb, 0, stream>>>(h_station, st_h, st_l, NS * D);
    zero2_kernel<<<gz, tpb, 0, stream>>>(deg_hf, deg_tt, NS);
    count_rank_kernel<<<ge, tpb, 0, stream>>>(hf_dst, tt_dst, deg_hf, deg_tt,
                                              rank_hf, rank_tt, E1, E2);
    scan_blocks_kernel<<<2 * nb, tpb, 0, stream>>>(deg_hf, rp_hf, bs_hf,
                                                   deg_tt, rp_tt, bs_tt, NS, nb);
    scan_offsets_kernel<<<2 * nb, tpb, 0, stream>>>(rp_hf, bs_hf, rp_tt, bs_tt,
                                                    NS, nb, E1, E2);
    fill_both_kernel<<<ge4, tpb, 0, stream>>>(hf_src, hf_dst, rank_hf, rp_hf, col_hf,
                                              tt_src, tt_dst, rank_tt, rp_tt, col_tt, E1, E2);

    int gagg  = (NS * 64 + tpb - 1) / tpb;
    int ggemm = (NS + 127) / 128;

    auto BI = [&](int lidx, int r) { return bias + (size_t)(lidx * 2 + r) * D; };
    auto WT = [&](int pair) { return wt + (size_t)pair * 65536; };

    float* out = (float*)d_out;

    // ---- layer 1 ----
    agg_mean_kernel<false><<<gagg, tpb, 0, stream>>>(h_feature, rp_hf, col_hf, n_h, n_l, NS);
    sage_mfma_kernel<false, false, true><<<ggemm, tpb, 0, stream>>>(
        st_h, st_l, n_h, n_l, WT(0), BI(0,0), nullptr, hb_h, hb_l, NS);
    agg_mean_kernel<true><<<gagg, tpb, 0, stream>>>(st_h, rp_tt, col_tt, n_h, n_l, NS);
    sage_mfma_kernel<true, false, true><<<ggemm, tpb, 0, stream>>>(
        st_h, st_l, n_h, n_l, WT(1), BI(0,1), nullptr, hb_h, hb_l, NS);

    // ---- layer 2 (in-place: blocks read only their own rows before writing) ----
    agg_mean_kernel<true><<<gagg, tpb, 0, stream>>>(hb_h, rp_tt, col_tt, n_h, n_l, NS);
    sage_mfma_kernel<false, false, true><<<ggemm, tpb, 0, stream>>>(
        hb_h, hb_l, n_h, n_l, WT(2), BI(1,1), nullptr, hb_h, hb_l, NS);

    // ---- layer 3 ----
    agg_mean_kernel<true><<<gagg, tpb, 0, stream>>>(hb_h, rp_tt, col_tt, n_h, n_l, NS);
    sage_mfma_kernel<false, true, false><<<ggemm, tpb, 0, stream>>>(
        hb_h, hb_l, n_h, n_l, WT(3), BI(2,1), out, nullptr, nullptr, NS);
}